// Round 7
// baseline (1981.998 us; speedup 1.0000x reference)
//
#include <hip/hip_runtime.h>
#include <hip/hip_bf16.h>
#include <stdint.h>

// QMIX+GAT round 7: R6 structure (lane=(sample,node), local softmax) with
// occupancy push to 3 blocks/CU: bf16 Wh exchange, XOR-swizzled wh2x,
// phase-3 tables unioned over phase-1 scratch, launch_bounds(256,3).

#define BT       (2048 * 128)
#define ALPHA    0.2f
#define NTILE    22            // 352 / 16
#define KSTEPS   16            // 512 / 32

typedef __attribute__((ext_vector_type(8))) short bf16x8;
typedef __attribute__((ext_vector_type(4))) float f32x4;

__device__ __forceinline__ float leaky(float x) { return x >= 0.f ? x : ALPHA * x; }
__device__ __forceinline__ float elu1(float x)  { return x > 0.f ? x : (__expf(x) - 1.f); }

__device__ __forceinline__ unsigned short f32_to_bf16_rne(float x) {
    uint32_t u = __float_as_uint(x);
    u += 0x7fffu + ((u >> 16) & 1u);
    return (unsigned short)(u >> 16);
}
__device__ __forceinline__ uint32_t pack2(float a, float b) {
    return (uint32_t)f32_to_bf16_rne(a) | ((uint32_t)f32_to_bf16_rne(b) << 16);
}
__device__ __forceinline__ float bf_lo(uint32_t u) { return __uint_as_float(u << 16); }
__device__ __forceinline__ float bf_hi(uint32_t u) { return __uint_as_float(u & 0xffff0000u); }

// softmax over 16 logits e1 + e2v[j]; e2v read from xch[32..47]; returns 1/sum
__device__ __forceinline__ float softmax16(const uint32_t* xch, float e1, float* ee) {
    #pragma unroll
    for (int t4 = 0; t4 < 4; ++t4) {
        const float4 v = *(const float4*)&xch[32 + t4 * 4];
        ee[4*t4+0] = leaky(e1 + v.x); ee[4*t4+1] = leaky(e1 + v.y);
        ee[4*t4+2] = leaky(e1 + v.z); ee[4*t4+3] = leaky(e1 + v.w);
    }
    float a0 = fmaxf(ee[0], ee[1]),   a1 = fmaxf(ee[2], ee[3]);
    float a2 = fmaxf(ee[4], ee[5]),   a3 = fmaxf(ee[6], ee[7]);
    float a4 = fmaxf(ee[8], ee[9]),   a5 = fmaxf(ee[10], ee[11]);
    float a6 = fmaxf(ee[12], ee[13]), a7 = fmaxf(ee[14], ee[15]);
    a0 = fmaxf(a0, a1); a2 = fmaxf(a2, a3); a4 = fmaxf(a4, a5); a6 = fmaxf(a6, a7);
    const float mx = fmaxf(fmaxf(a0, a2), fmaxf(a4, a6));
    #pragma unroll
    for (int j = 0; j < 16; ++j) ee[j] = __expf(ee[j] - mx);
    float s0 = ee[0]+ee[1], s1 = ee[2]+ee[3], s2 = ee[4]+ee[5], s3 = ee[6]+ee[7];
    float s4 = ee[8]+ee[9], s5 = ee[10]+ee[11], s6 = ee[12]+ee[13], s7 = ee[14]+ee[15];
    s0 += s1; s2 += s3; s4 += s5; s6 += s7;
    return 1.f / ((s0 + s2) + (s4 + s6));
}

// -------------------------------------------------- kernel P: pack B (bf16 frags)
__global__ __launch_bounds__(256) void pack_b(
    const float* __restrict__ hw1_w, const float* __restrict__ hb1_w,
    const float* __restrict__ hwf_w, const float* __restrict__ v1_w,
    unsigned short* __restrict__ bpack)
{
    const int gi = blockIdx.x * 256 + threadIdx.x;
    if (gi >= KSTEPS * NTILE * 64) return;
    const int l  = gi & 63;
    const int ni = (gi >> 6) % NTILE;
    const int kt = gi / (NTILE * 64);
    const int col = ni * 16 + (l & 15);
    const int k0  = kt * 32 + (l >> 4) * 8;
    const float* src; int stride; int c;
    if (col < 256)      { src = hw1_w; stride = 256; c = col; }
    else if (col < 288) { src = hb1_w; stride = 32;  c = col - 256; }
    else if (col < 320) { src = hwf_w; stride = 32;  c = col - 288; }
    else                { src = v1_w;  stride = 32;  c = col - 320; }
    union { unsigned short u[8]; uint4 v; } pk;
    #pragma unroll
    for (int e = 0; e < 8; ++e) pk.u[e] = f32_to_bf16_rne(src[(long)(k0 + e) * stride + c]);
    ((uint4*)bpack)[gi] = pk.v;
}

// -------------------------------------------------- kernel F
__global__ __launch_bounds__(256, 3) void fused_kernel(
    const float* __restrict__ agent_qs, const float* __restrict__ states,
    const float* __restrict__ W_heads,  const float* __restrict__ a_heads,
    const float* __restrict__ W_out,    const float* __restrict__ a_out,
    const unsigned short* __restrict__ bpack,
    const float* __restrict__ hw1_b, const float* __restrict__ hb1_b,
    const float* __restrict__ hwf_b, const float* __restrict__ v1_b,
    const float* __restrict__ v2_w,  const float* __restrict__ v2_b,
    float* __restrict__ out)
{
    __shared__ unsigned short A[32][512];       // 32 KB, rotation-swizzled chunks
    __shared__ union {
        struct {
            uint32_t xch[4][4][52];             // 0..31 Wh bf16-pairs, 32..47 e2 f32
            uint32_t wh2x[4][1036];             // g*260 + n*16 + xor-swizzled u32
        } p1;                                   // 19.4 KB (phase 1 only)
        struct {
            float bst[384];                     // hw1_b|hb1_b|hwf_b|v1_b|v2_w
            float qs[288];                      // stride 9
            float ysum[4][4][4];
        } p3;                                   // 2.9 KB (phase 3 only)
    } U;

    const int t    = threadIdx.x;
    const int w    = t >> 6;
    const int lane = t & 63;
    const int g    = lane >> 4;      // sample-in-quad
    const int n    = lane & 15;      // node / col
    const long sbase = (long)blockIdx.x * 32;

    uint32_t* xch = U.p1.xch[w][g];
    uint32_t* whp = &U.p1.wh2x[w][g * 260];

    // ---------------- phase 1: GAT, lane = (g=sample, n=node)
    #pragma unroll 1
    for (int q = 0; q < 2; ++q) {
        const int m = w * 8 + q * 4 + g;

        float xr[16];
        {
            const float4* xp = (const float4*)(states + (sbase + m) * 256 + n * 16);
            #pragma unroll
            for (int i = 0; i < 4; ++i) {
                const float4 v = xp[i];
                xr[4*i+0] = v.x; xr[4*i+1] = v.y; xr[4*i+2] = v.z; xr[4*i+3] = v.w;
            }
        }

        float hcat[16];
        #pragma unroll
        for (int h = 0; h < 4; ++h) {
            float wh0 = 0.f, wh1 = 0.f, wh2 = 0.f, wh3 = 0.f;
            #pragma unroll
            for (int f = 0; f < 16; ++f) {
                const float xf = xr[f];
                wh0 = fmaf(xf, W_heads[h*64 + f*4 + 0], wh0);
                wh1 = fmaf(xf, W_heads[h*64 + f*4 + 1], wh1);
                wh2 = fmaf(xf, W_heads[h*64 + f*4 + 2], wh2);
                wh3 = fmaf(xf, W_heads[h*64 + f*4 + 3], wh3);
            }
            const float e1 = wh0*a_heads[h*8+0] + wh1*a_heads[h*8+1]
                           + wh2*a_heads[h*8+2] + wh3*a_heads[h*8+3];
            const float e2 = wh0*a_heads[h*8+4] + wh1*a_heads[h*8+5]
                           + wh2*a_heads[h*8+6] + wh3*a_heads[h*8+7];
            uint2 wp; wp.x = pack2(wh0, wh1); wp.y = pack2(wh2, wh3);
            *(uint2*)&xch[n * 2] = wp;               // in-order DS, no barrier
            xch[32 + n] = __float_as_uint(e2);

            float ee[16];
            const float inv = softmax16(xch, e1, ee);

            float h0 = 0.f, h1 = 0.f, h2 = 0.f, h3 = 0.f;
            #pragma unroll
            for (int j = 0; j < 16; ++j) {
                const uint2 ww = *(const uint2*)&xch[j * 2];
                h0 = fmaf(ee[j], bf_lo(ww.x), h0);
                h1 = fmaf(ee[j], bf_hi(ww.x), h1);
                h2 = fmaf(ee[j], bf_lo(ww.y), h2);
                h3 = fmaf(ee[j], bf_hi(ww.y), h3);
            }
            hcat[h*4+0] = elu1(h0 * inv);
            hcat[h*4+1] = elu1(h1 * inv);
            hcat[h*4+2] = elu1(h2 * inv);
            hcat[h*4+3] = elu1(h3 * inv);
        }

        // ---- layer 2 projection; Wh2 row n exchanged as bf16, e1o/e2o folded
        float e1o = 0.f, e2o = 0.f;
        #pragma unroll 1
        for (int cq = 0; cq < 8; ++cq) {
            float wc0 = 0.f, wc1 = 0.f, wc2 = 0.f, wc3 = 0.f;
            #pragma unroll
            for (int f = 0; f < 16; ++f) {
                const float hv = hcat[f];
                wc0 = fmaf(hv, W_out[f*32 + cq*4 + 0], wc0);
                wc1 = fmaf(hv, W_out[f*32 + cq*4 + 1], wc1);
                wc2 = fmaf(hv, W_out[f*32 + cq*4 + 2], wc2);
                wc3 = fmaf(hv, W_out[f*32 + cq*4 + 3], wc3);
            }
            e1o += wc0*a_out[cq*4+0] + wc1*a_out[cq*4+1]
                 + wc2*a_out[cq*4+2] + wc3*a_out[cq*4+3];
            e2o += wc0*a_out[32+cq*4+0] + wc1*a_out[32+cq*4+1]
                 + wc2*a_out[32+cq*4+2] + wc3*a_out[32+cq*4+3];
            const int p2i = cq * 2;
            const int pp  = (p2i & 3) | ((p2i & ~3) ^ (((n >> 1) & 3) << 2));
            uint2 pw; pw.x = pack2(wc0, wc1); pw.y = pack2(wc2, wc3);
            *(uint2*)&whp[n * 16 + pp] = pw;
        }
        xch[32 + n] = __float_as_uint(e2o);

        float ee[16];
        const float invo = softmax16(xch, e1o, ee);

        // ---- aggregation in 2 halves of 16 cols (VGPR pressure)
        #pragma unroll 1
        for (int hf = 0; hf < 2; ++hf) {
            float gh[16];
            #pragma unroll
            for (int c = 0; c < 16; ++c) gh[c] = 0.f;
            #pragma unroll
            for (int j = 0; j < 16; ++j) {
                const int xorv = ((j >> 1) & 3) << 2;
                const uint4 wa = *(const uint4*)&whp[j*16 + ((hf*8)     ^ xorv)];
                const uint4 wb = *(const uint4*)&whp[j*16 + ((hf*8 + 4) ^ xorv)];
                const float aj = ee[j];
                gh[0]  = fmaf(aj, bf_lo(wa.x), gh[0]);  gh[1]  = fmaf(aj, bf_hi(wa.x), gh[1]);
                gh[2]  = fmaf(aj, bf_lo(wa.y), gh[2]);  gh[3]  = fmaf(aj, bf_hi(wa.y), gh[3]);
                gh[4]  = fmaf(aj, bf_lo(wa.z), gh[4]);  gh[5]  = fmaf(aj, bf_hi(wa.z), gh[5]);
                gh[6]  = fmaf(aj, bf_lo(wa.w), gh[6]);  gh[7]  = fmaf(aj, bf_hi(wa.w), gh[7]);
                gh[8]  = fmaf(aj, bf_lo(wb.x), gh[8]);  gh[9]  = fmaf(aj, bf_hi(wb.x), gh[9]);
                gh[10] = fmaf(aj, bf_lo(wb.y), gh[10]); gh[11] = fmaf(aj, bf_hi(wb.y), gh[11]);
                gh[12] = fmaf(aj, bf_lo(wb.z), gh[12]); gh[13] = fmaf(aj, bf_hi(wb.z), gh[13]);
                gh[14] = fmaf(aj, bf_lo(wb.w), gh[14]); gh[15] = fmaf(aj, bf_hi(wb.w), gh[15]);
            }
            #pragma unroll
            for (int k2 = 0; k2 < 2; ++k2) {
                const int kq = hf * 2 + k2;
                union { unsigned short us[8]; uint4 v; } pk;
                #pragma unroll
                for (int i2 = 0; i2 < 8; ++i2)
                    pk.us[i2] = f32_to_bf16_rne(elu1(gh[k2*8 + i2] * invo));
                const int chunk = (kq * 16 + n + m) & 63;   // rotation swizzle
                *(uint4*)((char*)&A[0][0] + m * 1024 + chunk * 16) = pk.v;
            }
        }
    }

    __syncthreads();   // phase-1 scratch dead; A complete

    // ---- stage phase-3 tables into registers (loads overlap MFMA loop)
    const float bv0 = hw1_b[t];
    float bv1 = 0.f;
    if (t < 32)       bv1 = hb1_b[t];
    else if (t < 64)  bv1 = hwf_b[t - 32];
    else if (t < 96)  bv1 = v1_b[t - 64];
    else if (t < 128) bv1 = v2_w[t - 96];
    const float qv = agent_qs[sbase * 8 + t];

    // ---------------- phase 2: MFMA GEMM, parity-split n-tiles
    const int mi  = w >> 1;
    const int pr  = w & 1;
    const int arow = mi * 16 + n;

    f32x4 acc[11];
    #pragma unroll
    for (int j = 0; j < 11; ++j) acc[j] = (f32x4){0.f, 0.f, 0.f, 0.f};

    const uint4* Bb = (const uint4*)bpack + lane;
    for (int kt = 0; kt < KSTEPS; ++kt) {
        const int chunk = (g * 16 + kt + arow) & 63;
        bf16x8 af = *(const bf16x8*)((const char*)&A[0][0] + arow * 1024 + chunk * 16);
        const uint4* bp = Bb + (kt * NTILE + pr) * 64;
        #pragma unroll
        for (int j = 0; j < 11; ++j) {
            uint4 bw = bp[(2 * j) * 64];
            bf16x8 bf;
            memcpy(&bf, &bw, 16);
            acc[j] = __builtin_amdgcn_mfma_f32_16x16x32_bf16(af, bf, acc[j], 0, 0, 0);
        }
    }

    // ---- write staged phase-3 tables (scratch now safe to overwrite)
    U.p3.bst[t] = bv0;
    if (t < 128) U.p3.bst[256 + t] = bv1;
    U.p3.qs[(t >> 3) * 9 + (t & 7)] = qv;
    __syncthreads();

    // ---------------- phase 3: epilogue from accumulators
    const int e = pr * 16 + n;
    float yp[4];
    #pragma unroll
    for (int r = 0; r < 4; ++r) {
        const int ms = mi * 16 + g * 4 + r;
        float hs = acc[8][r] + U.p3.bst[256 + e];
        #pragma unroll
        for (int a = 0; a < 8; ++a)
            hs = fmaf(U.p3.qs[ms * 9 + a], fabsf(acc[a][r] + U.p3.bst[a * 32 + e]), hs);
        const float hid = elu1(hs);
        yp[r] = hid * fabsf(acc[9][r] + U.p3.bst[288 + e])
              + fmaxf(acc[10][r] + U.p3.bst[320 + e], 0.f) * U.p3.bst[352 + e];
    }
    #pragma unroll
    for (int mask = 1; mask <= 8; mask <<= 1) {
        #pragma unroll
        for (int r = 0; r < 4; ++r) yp[r] += __shfl_xor(yp[r], mask);
    }
    if (n == 0) {
        #pragma unroll
        for (int r = 0; r < 4; ++r) U.p3.ysum[w][g][r] = yp[r];
    }
    __syncthreads();

    if (t < 32) {
        const int mi2 = t >> 4, g2 = (t >> 2) & 3, r2 = t & 3;
        out[sbase + t] = U.p3.ysum[mi2 * 2][g2][r2] + U.p3.ysum[mi2 * 2 + 1][g2][r2] + v2_b[0];
    }
}

// -------------------------------------------------- launch
extern "C" void kernel_launch(void* const* d_in, const int* in_sizes, int n_in,
                              void* d_out, int out_size, void* d_ws, size_t ws_size,
                              hipStream_t stream) {
    const float* agent_qs = (const float*)d_in[0];
    const float* states   = (const float*)d_in[1];
    const float* W_heads  = (const float*)d_in[2];
    const float* a_heads  = (const float*)d_in[3];
    const float* W_out    = (const float*)d_in[4];
    const float* a_out    = (const float*)d_in[5];
    const float* hw1_w    = (const float*)d_in[6];
    const float* hw1_b    = (const float*)d_in[7];
    const float* hb1_w    = (const float*)d_in[8];
    const float* hb1_b    = (const float*)d_in[9];
    const float* hwf_w    = (const float*)d_in[10];
    const float* hwf_b    = (const float*)d_in[11];
    const float* v1_w     = (const float*)d_in[12];
    const float* v1_b     = (const float*)d_in[13];
    const float* v2_w     = (const float*)d_in[14];
    const float* v2_b     = (const float*)d_in[15];

    unsigned short* bpack = (unsigned short*)d_ws;   // 360448 B used

    pack_b<<<(KSTEPS * NTILE * 64 + 255) / 256, 256, 0, stream>>>(hw1_w, hb1_w, hwf_w, v1_w, bpack);
    fused_kernel<<<BT / 32, 256, 0, stream>>>(agent_qs, states,
                                              W_heads, a_heads, W_out, a_out,
                                              bpack,
                                              hw1_b, hb1_b, hwf_b, v1_b, v2_w, v2_b,
                                              (float*)d_out);
}

// Round 8
// 845.342 us; speedup vs baseline: 2.3446x; 2.3446x over previous
//
#include <hip/hip_runtime.h>
#include <hip/hip_bf16.h>
#include <stdint.h>

// QMIX+GAT round 8: R7 LDS layout + PLAIN launch_bounds (R4/R7 lesson:
// min-waves arg => VGPR 84 + 4.5GB spill). New: dual-sample interleaved
// GAT head loop (samples A/B per lane, separate xch slots) to raise
// within-wave ILP at the fixed 2-waves/SIMD occupancy.

#define BT       (2048 * 128)
#define ALPHA    0.2f
#define NTILE    22            // 352 / 16
#define KSTEPS   16            // 512 / 32

typedef __attribute__((ext_vector_type(8))) short bf16x8;
typedef __attribute__((ext_vector_type(4))) float f32x4;

__device__ __forceinline__ float leaky(float x) { return x >= 0.f ? x : ALPHA * x; }
__device__ __forceinline__ float elu1(float x)  { return x > 0.f ? x : (__expf(x) - 1.f); }

__device__ __forceinline__ unsigned short f32_to_bf16_rne(float x) {
    uint32_t u = __float_as_uint(x);
    u += 0x7fffu + ((u >> 16) & 1u);
    return (unsigned short)(u >> 16);
}
__device__ __forceinline__ uint32_t pack2(float a, float b) {
    return (uint32_t)f32_to_bf16_rne(a) | ((uint32_t)f32_to_bf16_rne(b) << 16);
}
__device__ __forceinline__ float bf_lo(uint32_t u) { return __uint_as_float(u << 16); }
__device__ __forceinline__ float bf_hi(uint32_t u) { return __uint_as_float(u & 0xffff0000u); }

// softmax over 16 logits e1 + e2v[j]; e2v read from xch[32..47]; returns 1/sum
__device__ __forceinline__ float softmax16(const uint32_t* xch, float e1, float* ee) {
    #pragma unroll
    for (int t4 = 0; t4 < 4; ++t4) {
        const float4 v = *(const float4*)&xch[32 + t4 * 4];
        ee[4*t4+0] = leaky(e1 + v.x); ee[4*t4+1] = leaky(e1 + v.y);
        ee[4*t4+2] = leaky(e1 + v.z); ee[4*t4+3] = leaky(e1 + v.w);
    }
    float a0 = fmaxf(ee[0], ee[1]),   a1 = fmaxf(ee[2], ee[3]);
    float a2 = fmaxf(ee[4], ee[5]),   a3 = fmaxf(ee[6], ee[7]);
    float a4 = fmaxf(ee[8], ee[9]),   a5 = fmaxf(ee[10], ee[11]);
    float a6 = fmaxf(ee[12], ee[13]), a7 = fmaxf(ee[14], ee[15]);
    a0 = fmaxf(a0, a1); a2 = fmaxf(a2, a3); a4 = fmaxf(a4, a5); a6 = fmaxf(a6, a7);
    const float mx = fmaxf(fmaxf(a0, a2), fmaxf(a4, a6));
    #pragma unroll
    for (int j = 0; j < 16; ++j) ee[j] = __expf(ee[j] - mx);
    float s0 = ee[0]+ee[1], s1 = ee[2]+ee[3], s2 = ee[4]+ee[5], s3 = ee[6]+ee[7];
    float s4 = ee[8]+ee[9], s5 = ee[10]+ee[11], s6 = ee[12]+ee[13], s7 = ee[14]+ee[15];
    s0 += s1; s2 += s3; s4 += s5; s6 += s7;
    return 1.f / ((s0 + s2) + (s4 + s6));
}

// -------------------------------------------------- kernel P: pack B (bf16 frags)
__global__ __launch_bounds__(256) void pack_b(
    const float* __restrict__ hw1_w, const float* __restrict__ hb1_w,
    const float* __restrict__ hwf_w, const float* __restrict__ v1_w,
    unsigned short* __restrict__ bpack)
{
    const int gi = blockIdx.x * 256 + threadIdx.x;
    if (gi >= KSTEPS * NTILE * 64) return;
    const int l  = gi & 63;
    const int ni = (gi >> 6) % NTILE;
    const int kt = gi / (NTILE * 64);
    const int col = ni * 16 + (l & 15);
    const int k0  = kt * 32 + (l >> 4) * 8;
    const float* src; int stride; int c;
    if (col < 256)      { src = hw1_w; stride = 256; c = col; }
    else if (col < 288) { src = hb1_w; stride = 32;  c = col - 256; }
    else if (col < 320) { src = hwf_w; stride = 32;  c = col - 288; }
    else                { src = v1_w;  stride = 32;  c = col - 320; }
    union { unsigned short u[8]; uint4 v; } pk;
    #pragma unroll
    for (int e = 0; e < 8; ++e) pk.u[e] = f32_to_bf16_rne(src[(long)(k0 + e) * stride + c]);
    ((uint4*)bpack)[gi] = pk.v;
}

// -------------------------------------------------- kernel F
__global__ __launch_bounds__(256) void fused_kernel(
    const float* __restrict__ agent_qs, const float* __restrict__ states,
    const float* __restrict__ W_heads,  const float* __restrict__ a_heads,
    const float* __restrict__ W_out,    const float* __restrict__ a_out,
    const unsigned short* __restrict__ bpack,
    const float* __restrict__ hw1_b, const float* __restrict__ hb1_b,
    const float* __restrict__ hwf_b, const float* __restrict__ v1_b,
    const float* __restrict__ v2_w,  const float* __restrict__ v2_b,
    float* __restrict__ out)
{
    __shared__ unsigned short A[32][512];       // 32 KB, rotation-swizzled chunks
    __shared__ union {
        struct {
            uint32_t xch[4][8][52];             // [wave][g*2+s]: Wh pairs | e2
            uint32_t wh2x[4][1036];             // [wave]: g*260 + swizzled u32
        } p1;                                   // 23.2 KB (phase 1 only)
        struct {
            float bst[384];                     // hw1_b|hb1_b|hwf_b|v1_b|v2_w
            float qs[288];                      // stride 9
            float ysum[4][4][4];
        } p3;                                   // 2.9 KB (phase 3 only)
    } U;

    const int t    = threadIdx.x;
    const int w    = t >> 6;
    const int lane = t & 63;
    const int g    = lane >> 4;      // sample-in-quad
    const int n    = lane & 15;      // node / col
    const long sbase = (long)blockIdx.x * 32;

    uint32_t* xchA = U.p1.xch[w][g * 2];
    uint32_t* xchB = U.p1.xch[w][g * 2 + 1];
    uint32_t* whp  = &U.p1.wh2x[w][g * 260];

    const int mA = w * 8 + g;
    const int mB = w * 8 + 4 + g;

    // ---------------- phase 1: GAT, two samples per lane (A,B), interleaved
    float xrA[16], xrB[16];
    {
        const float4* xa = (const float4*)(states + (sbase + mA) * 256 + n * 16);
        const float4* xb = (const float4*)(states + (sbase + mB) * 256 + n * 16);
        #pragma unroll
        for (int i = 0; i < 4; ++i) {
            const float4 va = xa[i], vb = xb[i];
            xrA[4*i+0] = va.x; xrA[4*i+1] = va.y; xrA[4*i+2] = va.z; xrA[4*i+3] = va.w;
            xrB[4*i+0] = vb.x; xrB[4*i+1] = vb.y; xrB[4*i+2] = vb.z; xrB[4*i+3] = vb.w;
        }
    }

    float hcatA[16], hcatB[16];
    #pragma unroll
    for (int h = 0; h < 4; ++h) {
        float wa0 = 0.f, wa1 = 0.f, wa2 = 0.f, wa3 = 0.f;
        float wb0 = 0.f, wb1 = 0.f, wb2 = 0.f, wb3 = 0.f;
        #pragma unroll
        for (int f = 0; f < 16; ++f) {
            const float w0 = W_heads[h*64 + f*4 + 0];
            const float w1 = W_heads[h*64 + f*4 + 1];
            const float w2 = W_heads[h*64 + f*4 + 2];
            const float w3 = W_heads[h*64 + f*4 + 3];
            const float xa = xrA[f], xb = xrB[f];
            wa0 = fmaf(xa, w0, wa0); wb0 = fmaf(xb, w0, wb0);
            wa1 = fmaf(xa, w1, wa1); wb1 = fmaf(xb, w1, wb1);
            wa2 = fmaf(xa, w2, wa2); wb2 = fmaf(xb, w2, wb2);
            wa3 = fmaf(xa, w3, wa3); wb3 = fmaf(xb, w3, wb3);
        }
        const float e1A = wa0*a_heads[h*8+0] + wa1*a_heads[h*8+1]
                        + wa2*a_heads[h*8+2] + wa3*a_heads[h*8+3];
        const float e2A = wa0*a_heads[h*8+4] + wa1*a_heads[h*8+5]
                        + wa2*a_heads[h*8+6] + wa3*a_heads[h*8+7];
        const float e1B = wb0*a_heads[h*8+0] + wb1*a_heads[h*8+1]
                        + wb2*a_heads[h*8+2] + wb3*a_heads[h*8+3];
        const float e2B = wb0*a_heads[h*8+4] + wb1*a_heads[h*8+5]
                        + wb2*a_heads[h*8+6] + wb3*a_heads[h*8+7];
        {
            uint2 wp; wp.x = pack2(wa0, wa1); wp.y = pack2(wa2, wa3);
            *(uint2*)&xchA[n * 2] = wp;
            xchA[32 + n] = __float_as_uint(e2A);
        }
        {
            uint2 wp; wp.x = pack2(wb0, wb1); wp.y = pack2(wb2, wb3);
            *(uint2*)&xchB[n * 2] = wp;
            xchB[32 + n] = __float_as_uint(e2B);
        }

        float eeA[16], eeB[16];
        const float invA = softmax16(xchA, e1A, eeA);
        const float invB = softmax16(xchB, e1B, eeB);

        float hA0 = 0.f, hA1 = 0.f, hA2 = 0.f, hA3 = 0.f;
        float hB0 = 0.f, hB1 = 0.f, hB2 = 0.f, hB3 = 0.f;
        #pragma unroll
        for (int j = 0; j < 16; ++j) {
            const uint2 wwa = *(const uint2*)&xchA[j * 2];
            const uint2 wwb = *(const uint2*)&xchB[j * 2];
            hA0 = fmaf(eeA[j], bf_lo(wwa.x), hA0); hB0 = fmaf(eeB[j], bf_lo(wwb.x), hB0);
            hA1 = fmaf(eeA[j], bf_hi(wwa.x), hA1); hB1 = fmaf(eeB[j], bf_hi(wwb.x), hB1);
            hA2 = fmaf(eeA[j], bf_lo(wwa.y), hA2); hB2 = fmaf(eeB[j], bf_lo(wwb.y), hB2);
            hA3 = fmaf(eeA[j], bf_hi(wwa.y), hA3); hB3 = fmaf(eeB[j], bf_hi(wwb.y), hB3);
        }
        hcatA[h*4+0] = elu1(hA0 * invA); hcatB[h*4+0] = elu1(hB0 * invB);
        hcatA[h*4+1] = elu1(hA1 * invA); hcatB[h*4+1] = elu1(hB1 * invB);
        hcatA[h*4+2] = elu1(hA2 * invA); hcatB[h*4+2] = elu1(hB2 * invB);
        hcatA[h*4+3] = elu1(hA3 * invA); hcatB[h*4+3] = elu1(hB3 * invB);
    }

    // ---- layer 2, per sample (shared whp region: per-wave DS order is safe)
    auto layer2 = [&](const float* hcat, uint32_t* xch, int m) {
        float e1o = 0.f, e2o = 0.f;
        #pragma unroll 1
        for (int cq = 0; cq < 8; ++cq) {
            float wc0 = 0.f, wc1 = 0.f, wc2 = 0.f, wc3 = 0.f;
            #pragma unroll
            for (int f = 0; f < 16; ++f) {
                const float hv = hcat[f];
                wc0 = fmaf(hv, W_out[f*32 + cq*4 + 0], wc0);
                wc1 = fmaf(hv, W_out[f*32 + cq*4 + 1], wc1);
                wc2 = fmaf(hv, W_out[f*32 + cq*4 + 2], wc2);
                wc3 = fmaf(hv, W_out[f*32 + cq*4 + 3], wc3);
            }
            e1o += wc0*a_out[cq*4+0] + wc1*a_out[cq*4+1]
                 + wc2*a_out[cq*4+2] + wc3*a_out[cq*4+3];
            e2o += wc0*a_out[32+cq*4+0] + wc1*a_out[32+cq*4+1]
                 + wc2*a_out[32+cq*4+2] + wc3*a_out[32+cq*4+3];
            const int p2i = cq * 2;
            const int pp  = (p2i & 3) | ((p2i & ~3) ^ (((n >> 1) & 3) << 2));
            uint2 pw; pw.x = pack2(wc0, wc1); pw.y = pack2(wc2, wc3);
            *(uint2*)&whp[n * 16 + pp] = pw;
        }
        xch[32 + n] = __float_as_uint(e2o);

        float ee[16];
        const float invo = softmax16(xch, e1o, ee);

        #pragma unroll 1
        for (int hf = 0; hf < 2; ++hf) {
            float gh[16];
            #pragma unroll
            for (int c = 0; c < 16; ++c) gh[c] = 0.f;
            #pragma unroll
            for (int j = 0; j < 16; ++j) {
                const int xorv = ((j >> 1) & 3) << 2;
                const uint4 wa = *(const uint4*)&whp[j*16 + ((hf*8)     ^ xorv)];
                const uint4 wb = *(const uint4*)&whp[j*16 + ((hf*8 + 4) ^ xorv)];
                const float aj = ee[j];
                gh[0]  = fmaf(aj, bf_lo(wa.x), gh[0]);  gh[1]  = fmaf(aj, bf_hi(wa.x), gh[1]);
                gh[2]  = fmaf(aj, bf_lo(wa.y), gh[2]);  gh[3]  = fmaf(aj, bf_hi(wa.y), gh[3]);
                gh[4]  = fmaf(aj, bf_lo(wa.z), gh[4]);  gh[5]  = fmaf(aj, bf_hi(wa.z), gh[5]);
                gh[6]  = fmaf(aj, bf_lo(wa.w), gh[6]);  gh[7]  = fmaf(aj, bf_hi(wa.w), gh[7]);
                gh[8]  = fmaf(aj, bf_lo(wb.x), gh[8]);  gh[9]  = fmaf(aj, bf_hi(wb.x), gh[9]);
                gh[10] = fmaf(aj, bf_lo(wb.y), gh[10]); gh[11] = fmaf(aj, bf_hi(wb.y), gh[11]);
                gh[12] = fmaf(aj, bf_lo(wb.z), gh[12]); gh[13] = fmaf(aj, bf_hi(wb.z), gh[13]);
                gh[14] = fmaf(aj, bf_lo(wb.w), gh[14]); gh[15] = fmaf(aj, bf_hi(wb.w), gh[15]);
            }
            #pragma unroll
            for (int k2 = 0; k2 < 2; ++k2) {
                const int kq = hf * 2 + k2;
                union { unsigned short us[8]; uint4 v; } pk;
                #pragma unroll
                for (int i2 = 0; i2 < 8; ++i2)
                    pk.us[i2] = f32_to_bf16_rne(elu1(gh[k2*8 + i2] * invo));
                const int chunk = (kq * 16 + n + m) & 63;   // rotation swizzle
                *(uint4*)((char*)&A[0][0] + m * 1024 + chunk * 16) = pk.v;
            }
        }
    };
    layer2(hcatA, xchA, mA);
    layer2(hcatB, xchB, mB);

    __syncthreads();   // phase-1 scratch dead; A complete

    // ---- stage phase-3 tables into registers (loads overlap MFMA loop)
    const float bv0 = hw1_b[t];
    float bv1 = 0.f;
    if (t < 32)       bv1 = hb1_b[t];
    else if (t < 64)  bv1 = hwf_b[t - 32];
    else if (t < 96)  bv1 = v1_b[t - 64];
    else if (t < 128) bv1 = v2_w[t - 96];
    const float qv = agent_qs[sbase * 8 + t];

    // ---------------- phase 2: MFMA GEMM, parity-split n-tiles
    const int mi  = w >> 1;
    const int pr  = w & 1;
    const int arow = mi * 16 + n;

    f32x4 acc[11];
    #pragma unroll
    for (int j = 0; j < 11; ++j) acc[j] = (f32x4){0.f, 0.f, 0.f, 0.f};

    const uint4* Bb = (const uint4*)bpack + lane;
    for (int kt = 0; kt < KSTEPS; ++kt) {
        const int chunk = (g * 16 + kt + arow) & 63;
        bf16x8 af = *(const bf16x8*)((const char*)&A[0][0] + arow * 1024 + chunk * 16);
        const uint4* bp = Bb + (kt * NTILE + pr) * 64;
        #pragma unroll
        for (int j = 0; j < 11; ++j) {
            uint4 bw = bp[(2 * j) * 64];
            bf16x8 bf;
            memcpy(&bf, &bw, 16);
            acc[j] = __builtin_amdgcn_mfma_f32_16x16x32_bf16(af, bf, acc[j], 0, 0, 0);
        }
    }

    // ---- write staged phase-3 tables (scratch now safe to overwrite)
    U.p3.bst[t] = bv0;
    if (t < 128) U.p3.bst[256 + t] = bv1;
    U.p3.qs[(t >> 3) * 9 + (t & 7)] = qv;
    __syncthreads();

    // ---------------- phase 3: epilogue from accumulators
    const int e = pr * 16 + n;
    float yp[4];
    #pragma unroll
    for (int r = 0; r < 4; ++r) {
        const int ms = mi * 16 + g * 4 + r;
        float hs = acc[8][r] + U.p3.bst[256 + e];
        #pragma unroll
        for (int a = 0; a < 8; ++a)
            hs = fmaf(U.p3.qs[ms * 9 + a], fabsf(acc[a][r] + U.p3.bst[a * 32 + e]), hs);
        const float hid = elu1(hs);
        yp[r] = hid * fabsf(acc[9][r] + U.p3.bst[288 + e])
              + fmaxf(acc[10][r] + U.p3.bst[320 + e], 0.f) * U.p3.bst[352 + e];
    }
    #pragma unroll
    for (int mask = 1; mask <= 8; mask <<= 1) {
        #pragma unroll
        for (int r = 0; r < 4; ++r) yp[r] += __shfl_xor(yp[r], mask);
    }
    if (n == 0) {
        #pragma unroll
        for (int r = 0; r < 4; ++r) U.p3.ysum[w][g][r] = yp[r];
    }
    __syncthreads();

    if (t < 32) {
        const int mi2 = t >> 4, g2 = (t >> 2) & 3, r2 = t & 3;
        out[sbase + t] = U.p3.ysum[mi2 * 2][g2][r2] + U.p3.ysum[mi2 * 2 + 1][g2][r2] + v2_b[0];
    }
}

// -------------------------------------------------- launch
extern "C" void kernel_launch(void* const* d_in, const int* in_sizes, int n_in,
                              void* d_out, int out_size, void* d_ws, size_t ws_size,
                              hipStream_t stream) {
    const float* agent_qs = (const float*)d_in[0];
    const float* states   = (const float*)d_in[1];
    const float* W_heads  = (const float*)d_in[2];
    const float* a_heads  = (const float*)d_in[3];
    const float* W_out    = (const float*)d_in[4];
    const float* a_out    = (const float*)d_in[5];
    const float* hw1_w    = (const float*)d_in[6];
    const float* hw1_b    = (const float*)d_in[7];
    const float* hb1_w    = (const float*)d_in[8];
    const float* hb1_b    = (const float*)d_in[9];
    const float* hwf_w    = (const float*)d_in[10];
    const float* hwf_b    = (const float*)d_in[11];
    const float* v1_w     = (const float*)d_in[12];
    const float* v1_b     = (const float*)d_in[13];
    const float* v2_w     = (const float*)d_in[14];
    const float* v2_b     = (const float*)d_in[15];

    unsigned short* bpack = (unsigned short*)d_ws;   // 360448 B used

    pack_b<<<(KSTEPS * NTILE * 64 + 255) / 256, 256, 0, stream>>>(hw1_w, hb1_w, hwf_w, v1_w, bpack);
    fused_kernel<<<BT / 32, 256, 0, stream>>>(agent_qs, states,
                                              W_heads, a_heads, W_out, a_out,
                                              bpack,
                                              hw1_b, hb1_b, hwf_b, v1_b, v2_w, v2_b,
                                              (float*)d_out);
}

// Round 9
// 457.294 us; speedup vs baseline: 4.3342x; 1.8486x over previous
//
#include <hip/hip_runtime.h>
#include <hip/hip_bf16.h>
#include <stdint.h>

// QMIX+GAT round 9: R8 structure with PACKED f32 (v_pk_fma_f32) phase 1.
// A/B sample pair per lane carried as f32x2; all FMA chains via
// __builtin_elementwise_fma -> VOP3P. leaky as fmax(x,0.2x); softmax rcp.
// LDS: dual whp regions so agg2 is paired too (72.7 KB, 2 blocks/CU).
// Lesson ledger: NEVER pass min-waves>=2 in launch_bounds (R4/R7: VGPR 84 + spill).

#define BT       (2048 * 128)
#define ALPHA    0.2f
#define NTILE    22            // 352 / 16
#define KSTEPS   16            // 512 / 32

typedef __attribute__((ext_vector_type(8))) short bf16x8;
typedef __attribute__((ext_vector_type(4))) float f32x4;
typedef __attribute__((ext_vector_type(2))) float f32x2;

__device__ __forceinline__ f32x2 b2(float s) { return (f32x2){s, s}; }
__device__ __forceinline__ f32x2 pkfma(f32x2 a, f32x2 b, f32x2 c) {
    return __builtin_elementwise_fma(a, b, c);
}
__device__ __forceinline__ f32x2 leaky2(f32x2 v) {       // exact: ALPHA<1
    const f32x2 m = v * b2(ALPHA);
    return (f32x2){fmaxf(v.x, m.x), fmaxf(v.y, m.y)};
}
__device__ __forceinline__ float elu1(float x) { return x > 0.f ? x : (__expf(x) - 1.f); }

__device__ __forceinline__ unsigned short f32_to_bf16_rne(float x) {
    uint32_t u = __float_as_uint(x);
    u += 0x7fffu + ((u >> 16) & 1u);
    return (unsigned short)(u >> 16);
}
__device__ __forceinline__ uint32_t pack2(float a, float b) {
    return (uint32_t)f32_to_bf16_rne(a) | ((uint32_t)f32_to_bf16_rne(b) << 16);
}
__device__ __forceinline__ float bf_lo(uint32_t u) { return __uint_as_float(u << 16); }
__device__ __forceinline__ float bf_hi(uint32_t u) { return __uint_as_float(u & 0xffff0000u); }

// paired softmax over 16 logits; e2 rows read from xa[32..47], xb[32..47]
__device__ __forceinline__ f32x2 softmax16p(const uint32_t* xa, const uint32_t* xb,
                                            f32x2 e1, f32x2* ee) {
    #pragma unroll
    for (int t4 = 0; t4 < 4; ++t4) {
        const float4 va = *(const float4*)&xa[32 + t4 * 4];
        const float4 vb = *(const float4*)&xb[32 + t4 * 4];
        ee[4*t4+0] = leaky2(e1 + (f32x2){va.x, vb.x});
        ee[4*t4+1] = leaky2(e1 + (f32x2){va.y, vb.y});
        ee[4*t4+2] = leaky2(e1 + (f32x2){va.z, vb.z});
        ee[4*t4+3] = leaky2(e1 + (f32x2){va.w, vb.w});
    }
    f32x2 m0 = __builtin_elementwise_max(ee[0], ee[1]);
    f32x2 m1 = __builtin_elementwise_max(ee[2], ee[3]);
    f32x2 m2 = __builtin_elementwise_max(ee[4], ee[5]);
    f32x2 m3 = __builtin_elementwise_max(ee[6], ee[7]);
    f32x2 m4 = __builtin_elementwise_max(ee[8], ee[9]);
    f32x2 m5 = __builtin_elementwise_max(ee[10], ee[11]);
    f32x2 m6 = __builtin_elementwise_max(ee[12], ee[13]);
    f32x2 m7 = __builtin_elementwise_max(ee[14], ee[15]);
    m0 = __builtin_elementwise_max(m0, m1); m2 = __builtin_elementwise_max(m2, m3);
    m4 = __builtin_elementwise_max(m4, m5); m6 = __builtin_elementwise_max(m6, m7);
    const f32x2 mx = __builtin_elementwise_max(__builtin_elementwise_max(m0, m2),
                                               __builtin_elementwise_max(m4, m6));
    #pragma unroll
    for (int j = 0; j < 16; ++j) {
        const f32x2 d = ee[j] - mx;
        ee[j] = (f32x2){__expf(d.x), __expf(d.y)};
    }
    f32x2 s0 = ee[0]+ee[1], s1 = ee[2]+ee[3], s2 = ee[4]+ee[5], s3 = ee[6]+ee[7];
    f32x2 s4 = ee[8]+ee[9], s5 = ee[10]+ee[11], s6 = ee[12]+ee[13], s7 = ee[14]+ee[15];
    s0 += s1; s2 += s3; s4 += s5; s6 += s7;
    const f32x2 sum = (s0 + s2) + (s4 + s6);
    return (f32x2){__builtin_amdgcn_rcpf(sum.x), __builtin_amdgcn_rcpf(sum.y)};
}

// -------------------------------------------------- kernel P: pack B (bf16 frags)
__global__ __launch_bounds__(256) void pack_b(
    const float* __restrict__ hw1_w, const float* __restrict__ hb1_w,
    const float* __restrict__ hwf_w, const float* __restrict__ v1_w,
    unsigned short* __restrict__ bpack)
{
    const int gi = blockIdx.x * 256 + threadIdx.x;
    if (gi >= KSTEPS * NTILE * 64) return;
    const int l  = gi & 63;
    const int ni = (gi >> 6) % NTILE;
    const int kt = gi / (NTILE * 64);
    const int col = ni * 16 + (l & 15);
    const int k0  = kt * 32 + (l >> 4) * 8;
    const float* src; int stride; int c;
    if (col < 256)      { src = hw1_w; stride = 256; c = col; }
    else if (col < 288) { src = hb1_w; stride = 32;  c = col - 256; }
    else if (col < 320) { src = hwf_w; stride = 32;  c = col - 288; }
    else                { src = v1_w;  stride = 32;  c = col - 320; }
    union { unsigned short u[8]; uint4 v; } pk;
    #pragma unroll
    for (int e = 0; e < 8; ++e) pk.u[e] = f32_to_bf16_rne(src[(long)(k0 + e) * stride + c]);
    ((uint4*)bpack)[gi] = pk.v;
}

// -------------------------------------------------- kernel F
__global__ __launch_bounds__(256) void fused_kernel(
    const float* __restrict__ agent_qs, const float* __restrict__ states,
    const float* __restrict__ W_heads,  const float* __restrict__ a_heads,
    const float* __restrict__ W_out,    const float* __restrict__ a_out,
    const unsigned short* __restrict__ bpack,
    const float* __restrict__ hw1_b, const float* __restrict__ hb1_b,
    const float* __restrict__ hwf_b, const float* __restrict__ v1_b,
    const float* __restrict__ v2_w,  const float* __restrict__ v2_b,
    float* __restrict__ out)
{
    __shared__ unsigned short A[32][512];       // 32 KB, rotation-swizzled chunks
    __shared__ union {
        struct {
            uint32_t xch[4][8][52];             // [wave][g*2+s]: Wh pairs | e2
            uint32_t wh2x[4][8][260];           // [wave][g*2+s]: swizzled Wh2
        } p1;                                   // 39.9 KB (phase 1 only)
        struct {
            float bst[384];                     // hw1_b|hb1_b|hwf_b|v1_b|v2_w
            float qs[288];                      // stride 9
            float ysum[4][4][4];
        } p3;                                   // 2.9 KB (phase 3 only)
    } U;

    const int t    = threadIdx.x;
    const int w    = t >> 6;
    const int lane = t & 63;
    const int g    = lane >> 4;      // sample-in-quad
    const int n    = lane & 15;      // node / col
    const long sbase = (long)blockIdx.x * 32;

    uint32_t* xchA = U.p1.xch[w][g * 2];
    uint32_t* xchB = U.p1.xch[w][g * 2 + 1];
    uint32_t* whpA = U.p1.wh2x[w][g * 2];
    uint32_t* whpB = U.p1.wh2x[w][g * 2 + 1];

    const int mA = w * 8 + g;
    const int mB = w * 8 + 4 + g;

    // ---------------- phase 1: GAT, sample pair (A,B) as f32x2 lanes
    f32x2 xr2[16];
    {
        const float4* xa = (const float4*)(states + (sbase + mA) * 256 + n * 16);
        const float4* xb = (const float4*)(states + (sbase + mB) * 256 + n * 16);
        #pragma unroll
        for (int i = 0; i < 4; ++i) {
            const float4 va = xa[i], vb = xb[i];
            xr2[4*i+0] = (f32x2){va.x, vb.x};
            xr2[4*i+1] = (f32x2){va.y, vb.y};
            xr2[4*i+2] = (f32x2){va.z, vb.z};
            xr2[4*i+3] = (f32x2){va.w, vb.w};
        }
    }

    f32x2 hcat2[16];
    #pragma unroll
    for (int h = 0; h < 4; ++h) {
        f32x2 wh0 = b2(0.f), wh1 = b2(0.f), wh2 = b2(0.f), wh3 = b2(0.f);
        #pragma unroll
        for (int f = 0; f < 16; ++f) {
            const f32x2 xf = xr2[f];
            wh0 = pkfma(xf, b2(W_heads[h*64 + f*4 + 0]), wh0);
            wh1 = pkfma(xf, b2(W_heads[h*64 + f*4 + 1]), wh1);
            wh2 = pkfma(xf, b2(W_heads[h*64 + f*4 + 2]), wh2);
            wh3 = pkfma(xf, b2(W_heads[h*64 + f*4 + 3]), wh3);
        }
        const f32x2 e1 = pkfma(wh0, b2(a_heads[h*8+0]),
                         pkfma(wh1, b2(a_heads[h*8+1]),
                         pkfma(wh2, b2(a_heads[h*8+2]), wh3 * b2(a_heads[h*8+3]))));
        const f32x2 e2 = pkfma(wh0, b2(a_heads[h*8+4]),
                         pkfma(wh1, b2(a_heads[h*8+5]),
                         pkfma(wh2, b2(a_heads[h*8+6]), wh3 * b2(a_heads[h*8+7]))));
        {
            uint2 wp; wp.x = pack2(wh0.x, wh1.x); wp.y = pack2(wh2.x, wh3.x);
            *(uint2*)&xchA[n * 2] = wp;
            xchA[32 + n] = __float_as_uint(e2.x);
        }
        {
            uint2 wp; wp.x = pack2(wh0.y, wh1.y); wp.y = pack2(wh2.y, wh3.y);
            *(uint2*)&xchB[n * 2] = wp;
            xchB[32 + n] = __float_as_uint(e2.y);
        }

        f32x2 ee[16];
        const f32x2 inv = softmax16p(xchA, xchB, e1, ee);

        f32x2 h0 = b2(0.f), h1 = b2(0.f), h2 = b2(0.f), h3 = b2(0.f);
        #pragma unroll
        for (int j = 0; j < 16; ++j) {
            const uint2 wwa = *(const uint2*)&xchA[j * 2];
            const uint2 wwb = *(const uint2*)&xchB[j * 2];
            h0 = pkfma(ee[j], (f32x2){bf_lo(wwa.x), bf_lo(wwb.x)}, h0);
            h1 = pkfma(ee[j], (f32x2){bf_hi(wwa.x), bf_hi(wwb.x)}, h1);
            h2 = pkfma(ee[j], (f32x2){bf_lo(wwa.y), bf_lo(wwb.y)}, h2);
            h3 = pkfma(ee[j], (f32x2){bf_hi(wwa.y), bf_hi(wwb.y)}, h3);
        }
        h0 *= inv; h1 *= inv; h2 *= inv; h3 *= inv;
        hcat2[h*4+0] = (f32x2){elu1(h0.x), elu1(h0.y)};
        hcat2[h*4+1] = (f32x2){elu1(h1.x), elu1(h1.y)};
        hcat2[h*4+2] = (f32x2){elu1(h2.x), elu1(h2.y)};
        hcat2[h*4+3] = (f32x2){elu1(h3.x), elu1(h3.y)};
    }

    // ---- layer 2, paired: projection + e-folds + dual whp exchange
    f32x2 e1o = b2(0.f), e2o = b2(0.f);
    #pragma unroll 1
    for (int cq = 0; cq < 8; ++cq) {
        f32x2 wc0 = b2(0.f), wc1 = b2(0.f), wc2 = b2(0.f), wc3 = b2(0.f);
        #pragma unroll
        for (int f = 0; f < 16; ++f) {
            const f32x2 hv = hcat2[f];
            wc0 = pkfma(hv, b2(W_out[f*32 + cq*4 + 0]), wc0);
            wc1 = pkfma(hv, b2(W_out[f*32 + cq*4 + 1]), wc1);
            wc2 = pkfma(hv, b2(W_out[f*32 + cq*4 + 2]), wc2);
            wc3 = pkfma(hv, b2(W_out[f*32 + cq*4 + 3]), wc3);
        }
        e1o = pkfma(wc0, b2(a_out[cq*4+0]), pkfma(wc1, b2(a_out[cq*4+1]),
              pkfma(wc2, b2(a_out[cq*4+2]), pkfma(wc3, b2(a_out[cq*4+3]), e1o))));
        e2o = pkfma(wc0, b2(a_out[32+cq*4+0]), pkfma(wc1, b2(a_out[32+cq*4+1]),
              pkfma(wc2, b2(a_out[32+cq*4+2]), pkfma(wc3, b2(a_out[32+cq*4+3]), e2o))));
        const int p2i = cq * 2;
        const int pp  = (p2i & 3) | ((p2i & ~3) ^ (((n >> 1) & 3) << 2));
        {
            uint2 pw; pw.x = pack2(wc0.x, wc1.x); pw.y = pack2(wc2.x, wc3.x);
            *(uint2*)&whpA[n * 16 + pp] = pw;
        }
        {
            uint2 pw; pw.x = pack2(wc0.y, wc1.y); pw.y = pack2(wc2.y, wc3.y);
            *(uint2*)&whpB[n * 16 + pp] = pw;
        }
    }
    xchA[32 + n] = __float_as_uint(e2o.x);
    xchB[32 + n] = __float_as_uint(e2o.y);

    f32x2 ee[16];
    const f32x2 invo = softmax16p(xchA, xchB, e1o, ee);

    // ---- paired aggregation, 2 halves of 16 cols
    #pragma unroll 1
    for (int hf = 0; hf < 2; ++hf) {
        f32x2 gh[16];
        #pragma unroll
        for (int c = 0; c < 16; ++c) gh[c] = b2(0.f);
        #pragma unroll
        for (int j = 0; j < 16; ++j) {
            const int xorv = ((j >> 1) & 3) << 2;
            const uint4 waA = *(const uint4*)&whpA[j*16 + ((hf*8)     ^ xorv)];
            const uint4 wbA = *(const uint4*)&whpA[j*16 + ((hf*8 + 4) ^ xorv)];
            const uint4 waB = *(const uint4*)&whpB[j*16 + ((hf*8)     ^ xorv)];
            const uint4 wbB = *(const uint4*)&whpB[j*16 + ((hf*8 + 4) ^ xorv)];
            const f32x2 aj = ee[j];
            gh[0]  = pkfma(aj, (f32x2){bf_lo(waA.x), bf_lo(waB.x)}, gh[0]);
            gh[1]  = pkfma(aj, (f32x2){bf_hi(waA.x), bf_hi(waB.x)}, gh[1]);
            gh[2]  = pkfma(aj, (f32x2){bf_lo(waA.y), bf_lo(waB.y)}, gh[2]);
            gh[3]  = pkfma(aj, (f32x2){bf_hi(waA.y), bf_hi(waB.y)}, gh[3]);
            gh[4]  = pkfma(aj, (f32x2){bf_lo(waA.z), bf_lo(waB.z)}, gh[4]);
            gh[5]  = pkfma(aj, (f32x2){bf_hi(waA.z), bf_hi(waB.z)}, gh[5]);
            gh[6]  = pkfma(aj, (f32x2){bf_lo(waA.w), bf_lo(waB.w)}, gh[6]);
            gh[7]  = pkfma(aj, (f32x2){bf_hi(waA.w), bf_hi(waB.w)}, gh[7]);
            gh[8]  = pkfma(aj, (f32x2){bf_lo(wbA.x), bf_lo(wbB.x)}, gh[8]);
            gh[9]  = pkfma(aj, (f32x2){bf_hi(wbA.x), bf_hi(wbB.x)}, gh[9]);
            gh[10] = pkfma(aj, (f32x2){bf_lo(wbA.y), bf_lo(wbB.y)}, gh[10]);
            gh[11] = pkfma(aj, (f32x2){bf_hi(wbA.y), bf_hi(wbB.y)}, gh[11]);
            gh[12] = pkfma(aj, (f32x2){bf_lo(wbA.z), bf_lo(wbB.z)}, gh[12]);
            gh[13] = pkfma(aj, (f32x2){bf_hi(wbA.z), bf_hi(wbB.z)}, gh[13]);
            gh[14] = pkfma(aj, (f32x2){bf_lo(wbA.w), bf_lo(wbB.w)}, gh[14]);
            gh[15] = pkfma(aj, (f32x2){bf_hi(wbA.w), bf_hi(wbB.w)}, gh[15]);
        }
        #pragma unroll
        for (int c = 0; c < 16; ++c) gh[c] *= invo;
        #pragma unroll
        for (int k2 = 0; k2 < 2; ++k2) {
            const int kq = hf * 2 + k2;
            union { unsigned short us[8]; uint4 v; } pkA, pkB;
            #pragma unroll
            for (int i2 = 0; i2 < 8; ++i2) {
                pkA.us[i2] = f32_to_bf16_rne(elu1(gh[k2*8 + i2].x));
                pkB.us[i2] = f32_to_bf16_rne(elu1(gh[k2*8 + i2].y));
            }
            const int chunkA = (kq * 16 + n + mA) & 63;   // rotation swizzle
            const int chunkB = (kq * 16 + n + mB) & 63;
            *(uint4*)((char*)&A[0][0] + mA * 1024 + chunkA * 16) = pkA.v;
            *(uint4*)((char*)&A[0][0] + mB * 1024 + chunkB * 16) = pkB.v;
        }
    }

    __syncthreads();   // phase-1 scratch dead; A complete

    // ---- stage phase-3 tables into registers (loads overlap MFMA loop)
    const float bv0 = hw1_b[t];
    float bv1 = 0.f;
    if (t < 32)       bv1 = hb1_b[t];
    else if (t < 64)  bv1 = hwf_b[t - 32];
    else if (t < 96)  bv1 = v1_b[t - 64];
    else if (t < 128) bv1 = v2_w[t - 96];
    const float qv = agent_qs[sbase * 8 + t];

    // ---------------- phase 2: MFMA GEMM, parity-split n-tiles
    const int mi  = w >> 1;
    const int pr  = w & 1;
    const int arow = mi * 16 + n;

    f32x4 acc[11];
    #pragma unroll
    for (int j = 0; j < 11; ++j) acc[j] = (f32x4){0.f, 0.f, 0.f, 0.f};

    const uint4* Bb = (const uint4*)bpack + lane;
    for (int kt = 0; kt < KSTEPS; ++kt) {
        const int chunk = (g * 16 + kt + arow) & 63;
        bf16x8 af = *(const bf16x8*)((const char*)&A[0][0] + arow * 1024 + chunk * 16);
        const uint4* bp = Bb + (kt * NTILE + pr) * 64;
        #pragma unroll
        for (int j = 0; j < 11; ++j) {
            uint4 bw = bp[(2 * j) * 64];
            bf16x8 bf;
            memcpy(&bf, &bw, 16);
            acc[j] = __builtin_amdgcn_mfma_f32_16x16x32_bf16(af, bf, acc[j], 0, 0, 0);
        }
    }

    // ---- write staged phase-3 tables (scratch now safe to overwrite)
    U.p3.bst[t] = bv0;
    if (t < 128) U.p3.bst[256 + t] = bv1;
    U.p3.qs[(t >> 3) * 9 + (t & 7)] = qv;
    __syncthreads();

    // ---------------- phase 3: epilogue from accumulators
    const int e = pr * 16 + n;
    float yp[4];
    #pragma unroll
    for (int r = 0; r < 4; ++r) {
        const int ms = mi * 16 + g * 4 + r;
        float hs = acc[8][r] + U.p3.bst[256 + e];
        #pragma unroll
        for (int a = 0; a < 8; ++a)
            hs = fmaf(U.p3.qs[ms * 9 + a], fabsf(acc[a][r] + U.p3.bst[a * 32 + e]), hs);
        const float hid = elu1(hs);
        yp[r] = hid * fabsf(acc[9][r] + U.p3.bst[288 + e])
              + fmaxf(acc[10][r] + U.p3.bst[320 + e], 0.f) * U.p3.bst[352 + e];
    }
    #pragma unroll
    for (int mask = 1; mask <= 8; mask <<= 1) {
        #pragma unroll
        for (int r = 0; r < 4; ++r) yp[r] += __shfl_xor(yp[r], mask);
    }
    if (n == 0) {
        #pragma unroll
        for (int r = 0; r < 4; ++r) U.p3.ysum[w][g][r] = yp[r];
    }
    __syncthreads();

    if (t < 32) {
        const int mi2 = t >> 4, g2 = (t >> 2) & 3, r2 = t & 3;
        out[sbase + t] = U.p3.ysum[mi2 * 2][g2][r2] + U.p3.ysum[mi2 * 2 + 1][g2][r2] + v2_b[0];
    }
}

// -------------------------------------------------- launch
extern "C" void kernel_launch(void* const* d_in, const int* in_sizes, int n_in,
                              void* d_out, int out_size, void* d_ws, size_t ws_size,
                              hipStream_t stream) {
    const float* agent_qs = (const float*)d_in[0];
    const float* states   = (const float*)d_in[1];
    const float* W_heads  = (const float*)d_in[2];
    const float* a_heads  = (const float*)d_in[3];
    const float* W_out    = (const float*)d_in[4];
    const float* a_out    = (const float*)d_in[5];
    const float* hw1_w    = (const float*)d_in[6];
    const float* hw1_b    = (const float*)d_in[7];
    const float* hb1_w    = (const float*)d_in[8];
    const float* hb1_b    = (const float*)d_in[9];
    const float* hwf_w    = (const float*)d_in[10];
    const float* hwf_b    = (const float*)d_in[11];
    const float* v1_w     = (const float*)d_in[12];
    const float* v1_b     = (const float*)d_in[13];
    const float* v2_w     = (const float*)d_in[14];
    const float* v2_b     = (const float*)d_in[15];

    unsigned short* bpack = (unsigned short*)d_ws;   // 360448 B used

    pack_b<<<(KSTEPS * NTILE * 64 + 255) / 256, 256, 0, stream>>>(hw1_w, hb1_w, hwf_w, v1_w, bpack);
    fused_kernel<<<BT / 32, 256, 0, stream>>>(agent_qs, states,
                                              W_heads, a_heads, W_out, a_out,
                                              bpack,
                                              hw1_b, hb1_b, hwf_b, v1_b, v2_w, v2_b,
                                              (float*)d_out);
}

// Round 11
// 339.262 us; speedup vs baseline: 5.8421x; 1.3479x over previous
//
#include <hip/hip_runtime.h>
#include <hip/hip_bf16.h>
#include <stdint.h>

// QMIX+GAT round 11: R10 design (layer2 associativity, f16 LDS exchange,
// v_dot2_f32_f16) with the shufflevector -> uint4+bit_cast fix.
// Ledger: NEVER pass min-waves>=2 in launch_bounds (R4/R7: VGPR 84 + 4.5GB spill).

#define BT       (2048 * 128)
#define ALPHA    0.2f
#define NTILE    22            // 352 / 16
#define KSTEPS   16            // 512 / 32
#define AUXOFF   360448        // byte offset of wa1/wa2 aux table in d_ws

typedef __attribute__((ext_vector_type(8))) short bf16x8;
typedef __attribute__((ext_vector_type(4))) float f32x4;
typedef __attribute__((ext_vector_type(2))) float f32x2;
typedef _Float16 f16x2 __attribute__((ext_vector_type(2)));

__device__ __forceinline__ f32x2 b2(float s) { return (f32x2){s, s}; }
__device__ __forceinline__ f32x2 pkfma(f32x2 a, f32x2 b, f32x2 c) {
    return __builtin_elementwise_fma(a, b, c);
}
__device__ __forceinline__ float elu1(float x) { return x > 0.f ? x : (__expf(x) - 1.f); }

__device__ __forceinline__ unsigned short f32_to_bf16_rne(float x) {
    uint32_t u = __float_as_uint(x);
    u += 0x7fffu + ((u >> 16) & 1u);
    return (unsigned short)(u >> 16);
}

__device__ __forceinline__ float fdot2f(uint32_t a, f16x2 b, float c) {
#if __has_builtin(__builtin_amdgcn_fdot2)
    return __builtin_amdgcn_fdot2(__builtin_bit_cast(f16x2, a), b, c, false);
#else
    const f16x2 av = __builtin_bit_cast(f16x2, a);
    return fmaf((float)av.x, (float)b.x, fmaf((float)av.y, (float)b.y, c));
#endif
}
__device__ __forceinline__ f16x2 pkrtz(float a, float b) {
    return __builtin_bit_cast(f16x2, __builtin_amdgcn_cvt_pkrtz(a, b));
}
__device__ __forceinline__ uint32_t cvtpk_bf16(float lo, float hi) {
    uint32_t r;
    asm("v_cvt_pk_bf16_f32 %0, %1, %2" : "=v"(r) : "v"(lo), "v"(hi));
    return r;
}

// paired softmax over 16 logits e1 + e2[j]; returns {1/sumA, 1/sumB}
__device__ __forceinline__ f32x2 softmax16p(const float* e2A, const float* e2B,
                                            f32x2 e1, f32x2* ee) {
    #pragma unroll
    for (int t4 = 0; t4 < 4; ++t4) {
        const float4 va = *(const float4*)&e2A[t4 * 4];
        const float4 vb = *(const float4*)&e2B[t4 * 4];
        const f32x2 l0 = e1 + (f32x2){va.x, vb.x};
        const f32x2 l1 = e1 + (f32x2){va.y, vb.y};
        const f32x2 l2 = e1 + (f32x2){va.z, vb.z};
        const f32x2 l3 = e1 + (f32x2){va.w, vb.w};
        ee[4*t4+0] = __builtin_elementwise_max(l0, l0 * b2(ALPHA));
        ee[4*t4+1] = __builtin_elementwise_max(l1, l1 * b2(ALPHA));
        ee[4*t4+2] = __builtin_elementwise_max(l2, l2 * b2(ALPHA));
        ee[4*t4+3] = __builtin_elementwise_max(l3, l3 * b2(ALPHA));
    }
    f32x2 m0 = __builtin_elementwise_max(ee[0], ee[1]);
    f32x2 m1 = __builtin_elementwise_max(ee[2], ee[3]);
    f32x2 m2 = __builtin_elementwise_max(ee[4], ee[5]);
    f32x2 m3 = __builtin_elementwise_max(ee[6], ee[7]);
    f32x2 m4 = __builtin_elementwise_max(ee[8], ee[9]);
    f32x2 m5 = __builtin_elementwise_max(ee[10], ee[11]);
    f32x2 m6 = __builtin_elementwise_max(ee[12], ee[13]);
    f32x2 m7 = __builtin_elementwise_max(ee[14], ee[15]);
    m0 = __builtin_elementwise_max(m0, m1); m2 = __builtin_elementwise_max(m2, m3);
    m4 = __builtin_elementwise_max(m4, m5); m6 = __builtin_elementwise_max(m6, m7);
    const f32x2 mx = __builtin_elementwise_max(__builtin_elementwise_max(m0, m2),
                                               __builtin_elementwise_max(m4, m6));
    #pragma unroll
    for (int j = 0; j < 16; ++j) {
        const f32x2 d = ee[j] - mx;
        ee[j] = (f32x2){__expf(d.x), __expf(d.y)};
    }
    f32x2 s0 = ee[0]+ee[1], s1 = ee[2]+ee[3], s2 = ee[4]+ee[5], s3 = ee[6]+ee[7];
    f32x2 s4 = ee[8]+ee[9], s5 = ee[10]+ee[11], s6 = ee[12]+ee[13], s7 = ee[14]+ee[15];
    s0 += s1; s2 += s3; s4 += s5; s6 += s7;
    const f32x2 sum = (s0 + s2) + (s4 + s6);
    return (f32x2){__builtin_amdgcn_rcpf(sum.x), __builtin_amdgcn_rcpf(sum.y)};
}

// -------------------------------------------------- kernel P: pack B + aux
__global__ __launch_bounds__(256) void pack_b(
    const float* __restrict__ hw1_w, const float* __restrict__ hb1_w,
    const float* __restrict__ hwf_w, const float* __restrict__ v1_w,
    const float* __restrict__ W_out, const float* __restrict__ a_out,
    unsigned short* __restrict__ bpack, float* __restrict__ aux)
{
    const int gi = blockIdx.x * 256 + threadIdx.x;
    if (gi < KSTEPS * NTILE * 64) {
        const int l  = gi & 63;
        const int ni = (gi >> 6) % NTILE;
        const int kt = gi / (NTILE * 64);
        const int col = ni * 16 + (l & 15);
        const int k0  = kt * 32 + (l >> 4) * 8;
        const float* src; int stride; int c;
        if (col < 256)      { src = hw1_w; stride = 256; c = col; }
        else if (col < 288) { src = hb1_w; stride = 32;  c = col - 256; }
        else if (col < 320) { src = hwf_w; stride = 32;  c = col - 288; }
        else                { src = v1_w;  stride = 32;  c = col - 320; }
        union { unsigned short u[8]; uint4 v; } pk;
        #pragma unroll
        for (int e = 0; e < 8; ++e) pk.u[e] = f32_to_bf16_rne(src[(long)(k0 + e) * stride + c]);
        ((uint4*)bpack)[gi] = pk.v;
    } else if (gi < KSTEPS * NTILE * 64 + 32) {
        const int a = gi - KSTEPS * NTILE * 64;     // 0..31
        const int which = a >> 4, f = a & 15;
        float s = 0.f;
        for (int c = 0; c < 32; ++c) s = fmaf(W_out[f * 32 + c], a_out[which * 32 + c], s);
        aux[a] = s;                                  // wa1[16] | wa2[16]
    }
}

// -------------------------------------------------- kernel F
__global__ __launch_bounds__(256) void fused_kernel(
    const float* __restrict__ agent_qs, const float* __restrict__ states,
    const float* __restrict__ W_heads,  const float* __restrict__ a_heads,
    const float* __restrict__ W_out,    const float* __restrict__ a_out,
    const unsigned short* __restrict__ bpack, const float* __restrict__ aux,
    const float* __restrict__ hw1_b, const float* __restrict__ hb1_b,
    const float* __restrict__ hwf_b, const float* __restrict__ v1_b,
    const float* __restrict__ v2_w,  const float* __restrict__ v2_b,
    float* __restrict__ out)
{
    __shared__ unsigned short A[32][512];       // 32 KB, rotation-swizzled chunks
    __shared__ union {
        struct {
            _Float16 hx[4][8][264];             // [wave][slot] wh[k][n] / hcat[f][n]
            float    e2x[4][8][20];             // [wave][slot] e2 exchange
        } p1;                                   // 19.5 KB (phase 1 only)
        struct {
            float bst[384];                     // hw1_b|hb1_b|hwf_b|v1_b|v2_w
            float qs[288];                      // stride 9
            float ysum[4][4][4];
        } p3;
    } U;

    const int t    = threadIdx.x;
    const int w    = t >> 6;
    const int lane = t & 63;
    const int g    = lane >> 4;      // sample-in-quad
    const int n    = lane & 15;      // node / col
    const long sbase = (long)blockIdx.x * 32;

    _Float16* hxA = U.p1.hx[w][g * 2];
    _Float16* hxB = U.p1.hx[w][g * 2 + 1];
    float*    e2A = U.p1.e2x[w][g * 2];
    float*    e2B = U.p1.e2x[w][g * 2 + 1];

    const int mA = w * 8 + g;
    const int mB = w * 8 + 4 + g;

    // ---------------- phase 1: GAT, sample pair (A,B) as f32x2 lanes
    f32x2 xr2[16];
    {
        const float4* xa = (const float4*)(states + (sbase + mA) * 256 + n * 16);
        const float4* xb = (const float4*)(states + (sbase + mB) * 256 + n * 16);
        #pragma unroll
        for (int i = 0; i < 4; ++i) {
            const float4 va = xa[i], vb = xb[i];
            xr2[4*i+0] = (f32x2){va.x, vb.x};
            xr2[4*i+1] = (f32x2){va.y, vb.y};
            xr2[4*i+2] = (f32x2){va.z, vb.z};
            xr2[4*i+3] = (f32x2){va.w, vb.w};
        }
    }

    f32x2 hcat2[16];
    #pragma unroll
    for (int h = 0; h < 4; ++h) {
        f32x2 wh0 = b2(0.f), wh1 = b2(0.f), wh2 = b2(0.f), wh3 = b2(0.f);
        #pragma unroll
        for (int f = 0; f < 16; ++f) {
            const f32x2 xf = xr2[f];
            wh0 = pkfma(xf, b2(W_heads[h*64 + f*4 + 0]), wh0);
            wh1 = pkfma(xf, b2(W_heads[h*64 + f*4 + 1]), wh1);
            wh2 = pkfma(xf, b2(W_heads[h*64 + f*4 + 2]), wh2);
            wh3 = pkfma(xf, b2(W_heads[h*64 + f*4 + 3]), wh3);
        }
        const f32x2 e1 = pkfma(wh0, b2(a_heads[h*8+0]),
                         pkfma(wh1, b2(a_heads[h*8+1]),
                         pkfma(wh2, b2(a_heads[h*8+2]), wh3 * b2(a_heads[h*8+3]))));
        const f32x2 e2 = pkfma(wh0, b2(a_heads[h*8+4]),
                         pkfma(wh1, b2(a_heads[h*8+5]),
                         pkfma(wh2, b2(a_heads[h*8+6]), wh3 * b2(a_heads[h*8+7]))));
        // exchange wh rows as f16: layout [k][n]
        hxA[0*16 + n] = (_Float16)wh0.x;  hxB[0*16 + n] = (_Float16)wh0.y;
        hxA[1*16 + n] = (_Float16)wh1.x;  hxB[1*16 + n] = (_Float16)wh1.y;
        hxA[2*16 + n] = (_Float16)wh2.x;  hxB[2*16 + n] = (_Float16)wh2.y;
        hxA[3*16 + n] = (_Float16)wh3.x;  hxB[3*16 + n] = (_Float16)wh3.y;
        e2A[n] = e2.x;
        e2B[n] = e2.y;

        f32x2 ee[16];
        const f32x2 inv = softmax16p(e2A, e2B, e1, ee);
        f16x2 eA[8], eB[8];
        #pragma unroll
        for (int jp = 0; jp < 8; ++jp) {
            eA[jp] = pkrtz(ee[2*jp].x, ee[2*jp+1].x);
            eB[jp] = pkrtz(ee[2*jp].y, ee[2*jp+1].y);
        }
        // h[k] = sum_j ee[j] * wh[j][k] via dot2 (uint4 ds_read_b128, bit_cast)
        #pragma unroll
        for (int k = 0; k < 4; ++k) {
            const uint4 wa0 = *(const uint4*)&hxA[k*16];
            const uint4 wa1 = *(const uint4*)&hxA[k*16 + 8];
            const uint4 wb0 = *(const uint4*)&hxB[k*16];
            const uint4 wb1 = *(const uint4*)&hxB[k*16 + 8];
            float sA = 0.f, sB = 0.f;
            sA = fdot2f(wa0.x, eA[0], sA);  sB = fdot2f(wb0.x, eB[0], sB);
            sA = fdot2f(wa0.y, eA[1], sA);  sB = fdot2f(wb0.y, eB[1], sB);
            sA = fdot2f(wa0.z, eA[2], sA);  sB = fdot2f(wb0.z, eB[2], sB);
            sA = fdot2f(wa0.w, eA[3], sA);  sB = fdot2f(wb0.w, eB[3], sB);
            sA = fdot2f(wa1.x, eA[4], sA);  sB = fdot2f(wb1.x, eB[4], sB);
            sA = fdot2f(wa1.y, eA[5], sA);  sB = fdot2f(wb1.y, eB[5], sB);
            sA = fdot2f(wa1.z, eA[6], sA);  sB = fdot2f(wb1.z, eB[6], sB);
            sA = fdot2f(wa1.w, eA[7], sA);  sB = fdot2f(wb1.w, eB[7], sB);
            hcat2[h*4+k] = (f32x2){elu1(sA * inv.x), elu1(sB * inv.y)};
        }
    }

    // ---------------- layer 2: e-folds via aux, exchange hcat, agg, project
    f32x2 e1o = b2(0.f), e2o = b2(0.f);
    #pragma unroll
    for (int f = 0; f < 16; ++f) {
        e1o = pkfma(hcat2[f], b2(aux[f]), e1o);
        e2o = pkfma(hcat2[f], b2(aux[16 + f]), e2o);
    }
    #pragma unroll
    for (int f = 0; f < 16; ++f) {
        hxA[f*16 + n] = (_Float16)hcat2[f].x;
        hxB[f*16 + n] = (_Float16)hcat2[f].y;
    }
    e2A[n] = e2o.x;
    e2B[n] = e2o.y;

    f32x2 ee[16];
    const f32x2 invo = softmax16p(e2A, e2B, e1o, ee);
    f16x2 eA[8], eB[8];
    #pragma unroll
    for (int jp = 0; jp < 8; ++jp) {
        eA[jp] = pkrtz(ee[2*jp].x, ee[2*jp+1].x);
        eB[jp] = pkrtz(ee[2*jp].y, ee[2*jp+1].y);
    }
    // hagg[f] = sum_j ee[j] * hcat[j][f]
    f32x2 hagg[16];
    #pragma unroll
    for (int f = 0; f < 16; ++f) {
        const uint4 wa0 = *(const uint4*)&hxA[f*16];
        const uint4 wa1 = *(const uint4*)&hxA[f*16 + 8];
        const uint4 wb0 = *(const uint4*)&hxB[f*16];
        const uint4 wb1 = *(const uint4*)&hxB[f*16 + 8];
        float sA = 0.f, sB = 0.f;
        sA = fdot2f(wa0.x, eA[0], sA);  sB = fdot2f(wb0.x, eB[0], sB);
        sA = fdot2f(wa0.y, eA[1], sA);  sB = fdot2f(wb0.y, eB[1], sB);
        sA = fdot2f(wa0.z, eA[2], sA);  sB = fdot2f(wb0.z, eB[2], sB);
        sA = fdot2f(wa0.w, eA[3], sA);  sB = fdot2f(wb0.w, eB[3], sB);
        sA = fdot2f(wa1.x, eA[4], sA);  sB = fdot2f(wb1.x, eB[4], sB);
        sA = fdot2f(wa1.y, eA[5], sA);  sB = fdot2f(wb1.y, eB[5], sB);
        sA = fdot2f(wa1.z, eA[6], sA);  sB = fdot2f(wb1.z, eB[6], sB);
        sA = fdot2f(wa1.w, eA[7], sA);  sB = fdot2f(wb1.w, eB[7], sB);
        hagg[f] = (f32x2){sA, sB} * invo;
    }
    // gat = elu(hagg @ W_out), half at a time; pack bf16 -> A-tile
    #pragma unroll 1
    for (int hf = 0; hf < 2; ++hf) {
        f32x2 gh[16];
        #pragma unroll
        for (int c = 0; c < 16; ++c) gh[c] = b2(0.f);
        #pragma unroll
        for (int f = 0; f < 16; ++f) {
            const f32x2 hv = hagg[f];
            #pragma unroll
            for (int c = 0; c < 16; ++c)
                gh[c] = pkfma(hv, b2(W_out[f*32 + hf*16 + c]), gh[c]);
        }
        #pragma unroll
        for (int k2 = 0; k2 < 2; ++k2) {
            const int kq = hf * 2 + k2;
            float vA[8], vB[8];
            #pragma unroll
            for (int i2 = 0; i2 < 8; ++i2) {
                vA[i2] = elu1(gh[k2*8 + i2].x);
                vB[i2] = elu1(gh[k2*8 + i2].y);
            }
            uint4 pA, pB;
            pA.x = cvtpk_bf16(vA[0], vA[1]); pA.y = cvtpk_bf16(vA[2], vA[3]);
            pA.z = cvtpk_bf16(vA[4], vA[5]); pA.w = cvtpk_bf16(vA[6], vA[7]);
            pB.x = cvtpk_bf16(vB[0], vB[1]); pB.y = cvtpk_bf16(vB[2], vB[3]);
            pB.z = cvtpk_bf16(vB[4], vB[5]); pB.w = cvtpk_bf16(vB[6], vB[7]);
            const int chunkA = (kq * 16 + n + mA) & 63;   // rotation swizzle
            const int chunkB = (kq * 16 + n + mB) & 63;
            *(uint4*)((char*)&A[0][0] + mA * 1024 + chunkA * 16) = pA;
            *(uint4*)((char*)&A[0][0] + mB * 1024 + chunkB * 16) = pB;
        }
    }

    __syncthreads();   // phase-1 scratch dead; A complete

    // ---- stage phase-3 tables into registers (loads overlap MFMA loop)
    const float bv0 = hw1_b[t];
    float bv1 = 0.f;
    if (t < 32)       bv1 = hb1_b[t];
    else if (t < 64)  bv1 = hwf_b[t - 32];
    else if (t < 96)  bv1 = v1_b[t - 64];
    else if (t < 128) bv1 = v2_w[t - 96];
    const float qv = agent_qs[sbase * 8 + t];

    // ---------------- phase 2: MFMA GEMM, parity-split n-tiles (validated)
    const int mi  = w >> 1;
    const int pr  = w & 1;
    const int arow = mi * 16 + n;

    f32x4 acc[11];
    #pragma unroll
    for (int j = 0; j < 11; ++j) acc[j] = (f32x4){0.f, 0.f, 0.f, 0.f};

    const uint4* Bb = (const uint4*)bpack + lane;
    for (int kt = 0; kt < KSTEPS; ++kt) {
        const int chunk = (g * 16 + kt + arow) & 63;
        bf16x8 af = *(const bf16x8*)((const char*)&A[0][0] + arow * 1024 + chunk * 16);
        const uint4* bp = Bb + (kt * NTILE + pr) * 64;
        #pragma unroll
        for (int j = 0; j < 11; ++j) {
            uint4 bw = bp[(2 * j) * 64];
            bf16x8 bf;
            memcpy(&bf, &bw, 16);
            acc[j] = __builtin_amdgcn_mfma_f32_16x16x32_bf16(af, bf, acc[j], 0, 0, 0);
        }
    }

    // ---- write staged phase-3 tables (scratch now safe to overwrite)
    U.p3.bst[t] = bv0;
    if (t < 128) U.p3.bst[256 + t] = bv1;
    U.p3.qs[(t >> 3) * 9 + (t & 7)] = qv;
    __syncthreads();

    // ---------------- phase 3: epilogue from accumulators (validated)
    const int e = pr * 16 + n;
    float yp[4];
    #pragma unroll
    for (int r = 0; r < 4; ++r) {
        const int ms = mi * 16 + g * 4 + r;
        float hs = acc[8][r] + U.p3.bst[256 + e];
        #pragma unroll
        for (int a = 0; a < 8; ++a)
            hs = fmaf(U.p3.qs[ms * 9 + a], fabsf(acc[a][r] + U.p3.bst[a * 32 + e]), hs);
        const float hid = elu1(hs);
        yp[r] = hid * fabsf(acc[9][r] + U.p3.bst[288 + e])
              + fmaxf(acc[10][r] + U.p3.bst[320 + e], 0.f) * U.p3.bst[352 + e];
    }
    #pragma unroll
    for (int mask = 1; mask <= 8; mask <<= 1) {
        #pragma unroll
        for (int r = 0; r < 4; ++r) yp[r] += __shfl_xor(yp[r], mask);
    }
    if (n == 0) {
        #pragma unroll
        for (int r = 0; r < 4; ++r) U.p3.ysum[w][g][r] = yp[r];
    }
    __syncthreads();

    if (t < 32) {
        const int mi2 = t >> 4, g2 = (t >> 2) & 3, r2 = t & 3;
        out[sbase + t] = U.p3.ysum[mi2 * 2][g2][r2] + U.p3.ysum[mi2 * 2 + 1][g2][r2] + v2_b[0];
    }
}

// -------------------------------------------------- launch
extern "C" void kernel_launch(void* const* d_in, const int* in_sizes, int n_in,
                              void* d_out, int out_size, void* d_ws, size_t ws_size,
                              hipStream_t stream) {
    const float* agent_qs = (const float*)d_in[0];
    const float* states   = (const float*)d_in[1];
    const float* W_heads  = (const float*)d_in[2];
    const float* a_heads  = (const float*)d_in[3];
    const float* W_out    = (const float*)d_in[4];
    const float* a_out    = (const float*)d_in[5];
    const float* hw1_w    = (const float*)d_in[6];
    const float* hw1_b    = (const float*)d_in[7];
    const float* hb1_w    = (const float*)d_in[8];
    const float* hb1_b    = (const float*)d_in[9];
    const float* hwf_w    = (const float*)d_in[10];
    const float* hwf_b    = (const float*)d_in[11];
    const float* v1_w     = (const float*)d_in[12];
    const float* v1_b     = (const float*)d_in[13];
    const float* v2_w     = (const float*)d_in[14];
    const float* v2_b     = (const float*)d_in[15];

    unsigned short* bpack = (unsigned short*)d_ws;         // 360448 B
    float* aux = (float*)((char*)d_ws + AUXOFF);           // +128 B

    pack_b<<<(KSTEPS * NTILE * 64 + 32 + 255) / 256, 256, 0, stream>>>(
        hw1_w, hb1_w, hwf_w, v1_w, W_out, a_out, bpack, aux);
    fused_kernel<<<BT / 32, 256, 0, stream>>>(agent_qs, states,
                                              W_heads, a_heads, W_out, a_out,
                                              bpack, aux,
                                              hw1_b, hb1_b, hwf_b, v1_b, v2_w, v2_b,
                                              (float*)d_out);
}

// Round 12
// 336.757 us; speedup vs baseline: 5.8856x; 1.0074x over previous
//
#include <hip/hip_runtime.h>
#include <hip/hip_bf16.h>
#include <stdint.h>

// QMIX+GAT round 12: R11 + phase-1 scratch relocated INSIDE the A-tile rows
// this wave later overwrites (in-order DS within wave; reads precede writes).
// LDS 52.2 -> 35.7 KB => 4 blocks/CU.
// Ledger: NEVER pass min-waves>=2 in launch_bounds (R4/R7: VGPR 84 + 4.5GB spill).

#define BT       (2048 * 128)
#define ALPHA    0.2f
#define NTILE    22            // 352 / 16
#define KSTEPS   16            // 512 / 32
#define AUXOFF   360448        // byte offset of wa1/wa2 aux table in d_ws

typedef __attribute__((ext_vector_type(8))) short bf16x8;
typedef __attribute__((ext_vector_type(4))) float f32x4;
typedef __attribute__((ext_vector_type(2))) float f32x2;
typedef _Float16 f16x2 __attribute__((ext_vector_type(2)));

__device__ __forceinline__ f32x2 b2(float s) { return (f32x2){s, s}; }
__device__ __forceinline__ f32x2 pkfma(f32x2 a, f32x2 b, f32x2 c) {
    return __builtin_elementwise_fma(a, b, c);
}
__device__ __forceinline__ float elu1(float x) { return x > 0.f ? x : (__expf(x) - 1.f); }

__device__ __forceinline__ unsigned short f32_to_bf16_rne(float x) {
    uint32_t u = __float_as_uint(x);
    u += 0x7fffu + ((u >> 16) & 1u);
    return (unsigned short)(u >> 16);
}

__device__ __forceinline__ float fdot2f(uint32_t a, f16x2 b, float c) {
#if __has_builtin(__builtin_amdgcn_fdot2)
    return __builtin_amdgcn_fdot2(__builtin_bit_cast(f16x2, a), b, c, false);
#else
    const f16x2 av = __builtin_bit_cast(f16x2, a);
    return fmaf((float)av.x, (float)b.x, fmaf((float)av.y, (float)b.y, c));
#endif
}
__device__ __forceinline__ f16x2 pkrtz(float a, float b) {
    return __builtin_bit_cast(f16x2, __builtin_amdgcn_cvt_pkrtz(a, b));
}
__device__ __forceinline__ uint32_t cvtpk_bf16(float lo, float hi) {
    uint32_t r;
    asm("v_cvt_pk_bf16_f32 %0, %1, %2" : "=v"(r) : "v"(lo), "v"(hi));
    return r;
}

// paired softmax over 16 logits e1 + e2[j]; returns {1/sumA, 1/sumB}
__device__ __forceinline__ f32x2 softmax16p(const float* e2A, const float* e2B,
                                            f32x2 e1, f32x2* ee) {
    #pragma unroll
    for (int t4 = 0; t4 < 4; ++t4) {
        const float4 va = *(const float4*)&e2A[t4 * 4];
        const float4 vb = *(const float4*)&e2B[t4 * 4];
        const f32x2 l0 = e1 + (f32x2){va.x, vb.x};
        const f32x2 l1 = e1 + (f32x2){va.y, vb.y};
        const f32x2 l2 = e1 + (f32x2){va.z, vb.z};
        const f32x2 l3 = e1 + (f32x2){va.w, vb.w};
        ee[4*t4+0] = __builtin_elementwise_max(l0, l0 * b2(ALPHA));
        ee[4*t4+1] = __builtin_elementwise_max(l1, l1 * b2(ALPHA));
        ee[4*t4+2] = __builtin_elementwise_max(l2, l2 * b2(ALPHA));
        ee[4*t4+3] = __builtin_elementwise_max(l3, l3 * b2(ALPHA));
    }
    f32x2 m0 = __builtin_elementwise_max(ee[0], ee[1]);
    f32x2 m1 = __builtin_elementwise_max(ee[2], ee[3]);
    f32x2 m2 = __builtin_elementwise_max(ee[4], ee[5]);
    f32x2 m3 = __builtin_elementwise_max(ee[6], ee[7]);
    f32x2 m4 = __builtin_elementwise_max(ee[8], ee[9]);
    f32x2 m5 = __builtin_elementwise_max(ee[10], ee[11]);
    f32x2 m6 = __builtin_elementwise_max(ee[12], ee[13]);
    f32x2 m7 = __builtin_elementwise_max(ee[14], ee[15]);
    m0 = __builtin_elementwise_max(m0, m1); m2 = __builtin_elementwise_max(m2, m3);
    m4 = __builtin_elementwise_max(m4, m5); m6 = __builtin_elementwise_max(m6, m7);
    const f32x2 mx = __builtin_elementwise_max(__builtin_elementwise_max(m0, m2),
                                               __builtin_elementwise_max(m4, m6));
    #pragma unroll
    for (int j = 0; j < 16; ++j) {
        const f32x2 d = ee[j] - mx;
        ee[j] = (f32x2){__expf(d.x), __expf(d.y)};
    }
    f32x2 s0 = ee[0]+ee[1], s1 = ee[2]+ee[3], s2 = ee[4]+ee[5], s3 = ee[6]+ee[7];
    f32x2 s4 = ee[8]+ee[9], s5 = ee[10]+ee[11], s6 = ee[12]+ee[13], s7 = ee[14]+ee[15];
    s0 += s1; s2 += s3; s4 += s5; s6 += s7;
    const f32x2 sum = (s0 + s2) + (s4 + s6);
    return (f32x2){__builtin_amdgcn_rcpf(sum.x), __builtin_amdgcn_rcpf(sum.y)};
}

// -------------------------------------------------- kernel P: pack B + aux
__global__ __launch_bounds__(256) void pack_b(
    const float* __restrict__ hw1_w, const float* __restrict__ hb1_w,
    const float* __restrict__ hwf_w, const float* __restrict__ v1_w,
    const float* __restrict__ W_out, const float* __restrict__ a_out,
    unsigned short* __restrict__ bpack, float* __restrict__ aux)
{
    const int gi = blockIdx.x * 256 + threadIdx.x;
    if (gi < KSTEPS * NTILE * 64) {
        const int l  = gi & 63;
        const int ni = (gi >> 6) % NTILE;
        const int kt = gi / (NTILE * 64);
        const int col = ni * 16 + (l & 15);
        const int k0  = kt * 32 + (l >> 4) * 8;
        const float* src; int stride; int c;
        if (col < 256)      { src = hw1_w; stride = 256; c = col; }
        else if (col < 288) { src = hb1_w; stride = 32;  c = col - 256; }
        else if (col < 320) { src = hwf_w; stride = 32;  c = col - 288; }
        else                { src = v1_w;  stride = 32;  c = col - 320; }
        union { unsigned short u[8]; uint4 v; } pk;
        #pragma unroll
        for (int e = 0; e < 8; ++e) pk.u[e] = f32_to_bf16_rne(src[(long)(k0 + e) * stride + c]);
        ((uint4*)bpack)[gi] = pk.v;
    } else if (gi < KSTEPS * NTILE * 64 + 32) {
        const int a = gi - KSTEPS * NTILE * 64;     // 0..31
        const int which = a >> 4, f = a & 15;
        float s = 0.f;
        for (int c = 0; c < 32; ++c) s = fmaf(W_out[f * 32 + c], a_out[which * 32 + c], s);
        aux[a] = s;                                  // wa1[16] | wa2[16]
    }
}

// -------------------------------------------------- kernel F
__global__ __launch_bounds__(256) void fused_kernel(
    const float* __restrict__ agent_qs, const float* __restrict__ states,
    const float* __restrict__ W_heads,  const float* __restrict__ a_heads,
    const float* __restrict__ W_out,    const float* __restrict__ a_out,
    const unsigned short* __restrict__ bpack, const float* __restrict__ aux,
    const float* __restrict__ hw1_b, const float* __restrict__ hb1_b,
    const float* __restrict__ hwf_b, const float* __restrict__ v1_b,
    const float* __restrict__ v2_w,  const float* __restrict__ v2_b,
    float* __restrict__ out)
{
    __shared__ unsigned short A[32][512];  // 32 KB; rows w*8..w*8+7 double as
                                           // wave-w phase-1 scratch (written last)
    __shared__ float bst[384];             // hw1_b|hb1_b|hwf_b|v1_b|v2_w
    __shared__ float qs[288];              // stride 9
    __shared__ float ysum[4][4][4];

    const int t    = threadIdx.x;
    const int w    = t >> 6;
    const int lane = t & 63;
    const int g    = lane >> 4;      // sample-in-quad
    const int n    = lane & 15;      // node / col
    const long sbase = (long)blockIdx.x * 32;

    // phase-1 scratch inside this wave's A rows (8 KB region):
    //   hx slots: 8 x 528 B at +0 .. +4224 ; e2 slots: 8 x 80 B at +4224
    char* scr = (char*)&A[0][0] + w * 8192;
    _Float16* hxA = (_Float16*)(scr + (g * 2)     * 528);
    _Float16* hxB = (_Float16*)(scr + (g * 2 + 1) * 528);
    float*    e2A = (float*)(scr + 4224 + (g * 2)     * 80);
    float*    e2B = (float*)(scr + 4224 + (g * 2 + 1) * 80);

    const int mA = w * 8 + g;
    const int mB = w * 8 + 4 + g;

    // ---------------- phase 1: GAT, sample pair (A,B) as f32x2 lanes
    f32x2 xr2[16];
    {
        const float4* xa = (const float4*)(states + (sbase + mA) * 256 + n * 16);
        const float4* xb = (const float4*)(states + (sbase + mB) * 256 + n * 16);
        #pragma unroll
        for (int i = 0; i < 4; ++i) {
            const float4 va = xa[i], vb = xb[i];
            xr2[4*i+0] = (f32x2){va.x, vb.x};
            xr2[4*i+1] = (f32x2){va.y, vb.y};
            xr2[4*i+2] = (f32x2){va.z, vb.z};
            xr2[4*i+3] = (f32x2){va.w, vb.w};
        }
    }

    f32x2 hcat2[16];
    #pragma unroll
    for (int h = 0; h < 4; ++h) {
        f32x2 wh0 = b2(0.f), wh1 = b2(0.f), wh2 = b2(0.f), wh3 = b2(0.f);
        #pragma unroll
        for (int f = 0; f < 16; ++f) {
            const f32x2 xf = xr2[f];
            wh0 = pkfma(xf, b2(W_heads[h*64 + f*4 + 0]), wh0);
            wh1 = pkfma(xf, b2(W_heads[h*64 + f*4 + 1]), wh1);
            wh2 = pkfma(xf, b2(W_heads[h*64 + f*4 + 2]), wh2);
            wh3 = pkfma(xf, b2(W_heads[h*64 + f*4 + 3]), wh3);
        }
        const f32x2 e1 = pkfma(wh0, b2(a_heads[h*8+0]),
                         pkfma(wh1, b2(a_heads[h*8+1]),
                         pkfma(wh2, b2(a_heads[h*8+2]), wh3 * b2(a_heads[h*8+3]))));
        const f32x2 e2 = pkfma(wh0, b2(a_heads[h*8+4]),
                         pkfma(wh1, b2(a_heads[h*8+5]),
                         pkfma(wh2, b2(a_heads[h*8+6]), wh3 * b2(a_heads[h*8+7]))));
        // exchange wh rows as f16: layout [k][n]
        hxA[0*16 + n] = (_Float16)wh0.x;  hxB[0*16 + n] = (_Float16)wh0.y;
        hxA[1*16 + n] = (_Float16)wh1.x;  hxB[1*16 + n] = (_Float16)wh1.y;
        hxA[2*16 + n] = (_Float16)wh2.x;  hxB[2*16 + n] = (_Float16)wh2.y;
        hxA[3*16 + n] = (_Float16)wh3.x;  hxB[3*16 + n] = (_Float16)wh3.y;
        e2A[n] = e2.x;
        e2B[n] = e2.y;

        f32x2 ee[16];
        const f32x2 inv = softmax16p(e2A, e2B, e1, ee);
        f16x2 eA[8], eB[8];
        #pragma unroll
        for (int jp = 0; jp < 8; ++jp) {
            eA[jp] = pkrtz(ee[2*jp].x, ee[2*jp+1].x);
            eB[jp] = pkrtz(ee[2*jp].y, ee[2*jp+1].y);
        }
        // h[k] = sum_j ee[j] * wh[j][k] via dot2 (uint4 ds_read_b128, bit_cast)
        #pragma unroll
        for (int k = 0; k < 4; ++k) {
            const uint4 wa0 = *(const uint4*)&hxA[k*16];
            const uint4 wa1 = *(const uint4*)&hxA[k*16 + 8];
            const uint4 wb0 = *(const uint4*)&hxB[k*16];
            const uint4 wb1 = *(const uint4*)&hxB[k*16 + 8];
            float sA = 0.f, sB = 0.f;
            sA = fdot2f(wa0.x, eA[0], sA);  sB = fdot2f(wb0.x, eB[0], sB);
            sA = fdot2f(wa0.y, eA[1], sA);  sB = fdot2f(wb0.y, eB[1], sB);
            sA = fdot2f(wa0.z, eA[2], sA);  sB = fdot2f(wb0.z, eB[2], sB);
            sA = fdot2f(wa0.w, eA[3], sA);  sB = fdot2f(wb0.w, eB[3], sB);
            sA = fdot2f(wa1.x, eA[4], sA);  sB = fdot2f(wb1.x, eB[4], sB);
            sA = fdot2f(wa1.y, eA[5], sA);  sB = fdot2f(wb1.y, eB[5], sB);
            sA = fdot2f(wa1.z, eA[6], sA);  sB = fdot2f(wb1.z, eB[6], sB);
            sA = fdot2f(wa1.w, eA[7], sA);  sB = fdot2f(wb1.w, eB[7], sB);
            hcat2[h*4+k] = (f32x2){elu1(sA * inv.x), elu1(sB * inv.y)};
        }
    }

    // ---------------- layer 2: e-folds via aux, exchange hcat, agg, project
    f32x2 e1o = b2(0.f), e2o = b2(0.f);
    #pragma unroll
    for (int f = 0; f < 16; ++f) {
        e1o = pkfma(hcat2[f], b2(aux[f]), e1o);
        e2o = pkfma(hcat2[f], b2(aux[16 + f]), e2o);
    }
    #pragma unroll
    for (int f = 0; f < 16; ++f) {
        hxA[f*16 + n] = (_Float16)hcat2[f].x;
        hxB[f*16 + n] = (_Float16)hcat2[f].y;
    }
    e2A[n] = e2o.x;
    e2B[n] = e2o.y;

    f32x2 ee[16];
    const f32x2 invo = softmax16p(e2A, e2B, e1o, ee);
    f16x2 eA[8], eB[8];
    #pragma unroll
    for (int jp = 0; jp < 8; ++jp) {
        eA[jp] = pkrtz(ee[2*jp].x, ee[2*jp+1].x);
        eB[jp] = pkrtz(ee[2*jp].y, ee[2*jp+1].y);
    }
    // hagg[f] = sum_j ee[j] * hcat[j][f]
    f32x2 hagg[16];
    #pragma unroll
    for (int f = 0; f < 16; ++f) {
        const uint4 wa0 = *(const uint4*)&hxA[f*16];
        const uint4 wa1 = *(const uint4*)&hxA[f*16 + 8];
        const uint4 wb0 = *(const uint4*)&hxB[f*16];
        const uint4 wb1 = *(const uint4*)&hxB[f*16 + 8];
        float sA = 0.f, sB = 0.f;
        sA = fdot2f(wa0.x, eA[0], sA);  sB = fdot2f(wb0.x, eB[0], sB);
        sA = fdot2f(wa0.y, eA[1], sA);  sB = fdot2f(wb0.y, eB[1], sB);
        sA = fdot2f(wa0.z, eA[2], sA);  sB = fdot2f(wb0.z, eB[2], sB);
        sA = fdot2f(wa0.w, eA[3], sA);  sB = fdot2f(wb0.w, eB[3], sB);
        sA = fdot2f(wa1.x, eA[4], sA);  sB = fdot2f(wb1.x, eB[4], sB);
        sA = fdot2f(wa1.y, eA[5], sA);  sB = fdot2f(wb1.y, eB[5], sB);
        sA = fdot2f(wa1.z, eA[6], sA);  sB = fdot2f(wb1.z, eB[6], sB);
        sA = fdot2f(wa1.w, eA[7], sA);  sB = fdot2f(wb1.w, eB[7], sB);
        hagg[f] = (f32x2){sA, sB} * invo;
    }
    // gat = elu(hagg @ W_out), half at a time; pack bf16 -> A-tile
    // (A-row stores strictly follow all scratch reads in program order)
    #pragma unroll 1
    for (int hf = 0; hf < 2; ++hf) {
        f32x2 gh[16];
        #pragma unroll
        for (int c = 0; c < 16; ++c) gh[c] = b2(0.f);
        #pragma unroll
        for (int f = 0; f < 16; ++f) {
            const f32x2 hv = hagg[f];
            #pragma unroll
            for (int c = 0; c < 16; ++c)
                gh[c] = pkfma(hv, b2(W_out[f*32 + hf*16 + c]), gh[c]);
        }
        #pragma unroll
        for (int k2 = 0; k2 < 2; ++k2) {
            const int kq = hf * 2 + k2;
            float vA[8], vB[8];
            #pragma unroll
            for (int i2 = 0; i2 < 8; ++i2) {
                vA[i2] = elu1(gh[k2*8 + i2].x);
                vB[i2] = elu1(gh[k2*8 + i2].y);
            }
            uint4 pA, pB;
            pA.x = cvtpk_bf16(vA[0], vA[1]); pA.y = cvtpk_bf16(vA[2], vA[3]);
            pA.z = cvtpk_bf16(vA[4], vA[5]); pA.w = cvtpk_bf16(vA[6], vA[7]);
            pB.x = cvtpk_bf16(vB[0], vB[1]); pB.y = cvtpk_bf16(vB[2], vB[3]);
            pB.z = cvtpk_bf16(vB[4], vB[5]); pB.w = cvtpk_bf16(vB[6], vB[7]);
            const int chunkA = (kq * 16 + n + mA) & 63;   // rotation swizzle
            const int chunkB = (kq * 16 + n + mB) & 63;
            *(uint4*)((char*)&A[0][0] + mA * 1024 + chunkA * 16) = pA;
            *(uint4*)((char*)&A[0][0] + mB * 1024 + chunkB * 16) = pB;
        }
    }

    __syncthreads();   // all A rows final; cross-wave reads now safe

    // ---- stage phase-3 tables into registers (loads overlap MFMA loop)
    const float bv0 = hw1_b[t];
    float bv1 = 0.f;
    if (t < 32)       bv1 = hb1_b[t];
    else if (t < 64)  bv1 = hwf_b[t - 32];
    else if (t < 96)  bv1 = v1_b[t - 64];
    else if (t < 128) bv1 = v2_w[t - 96];
    const float qv = agent_qs[sbase * 8 + t];

    // ---------------- phase 2: MFMA GEMM, parity-split n-tiles (validated)
    const int mi  = w >> 1;
    const int pr  = w & 1;
    const int arow = mi * 16 + n;

    f32x4 acc[11];
    #pragma unroll
    for (int j = 0; j < 11; ++j) acc[j] = (f32x4){0.f, 0.f, 0.f, 0.f};

    const uint4* Bb = (const uint4*)bpack + lane;
    for (int kt = 0; kt < KSTEPS; ++kt) {
        const int chunk = (g * 16 + kt + arow) & 63;
        bf16x8 af = *(const bf16x8*)((const char*)&A[0][0] + arow * 1024 + chunk * 16);
        const uint4* bp = Bb + (kt * NTILE + pr) * 64;
        #pragma unroll
        for (int j = 0; j < 11; ++j) {
            uint4 bw = bp[(2 * j) * 64];
            bf16x8 bf;
            memcpy(&bf, &bw, 16);
            acc[j] = __builtin_amdgcn_mfma_f32_16x16x32_bf16(af, bf, acc[j], 0, 0, 0);
        }
    }

    // ---- write staged phase-3 tables (separate LDS region, A still live)
    bst[t] = bv0;
    if (t < 128) bst[256 + t] = bv1;
    qs[(t >> 3) * 9 + (t & 7)] = qv;
    __syncthreads();

    // ---------------- phase 3: epilogue from accumulators (validated)
    const int e = pr * 16 + n;
    float yp[4];
    #pragma unroll
    for (int r = 0; r < 4; ++r) {
        const int ms = mi * 16 + g * 4 + r;
        float hs = acc[8][r] + bst[256 + e];
        #pragma unroll
        for (int a = 0; a < 8; ++a)
            hs = fmaf(qs[ms * 9 + a], fabsf(acc[a][r] + bst[a * 32 + e]), hs);
        const float hid = elu1(hs);
        yp[r] = hid * fabsf(acc[9][r] + bst[288 + e])
              + fmaxf(acc[10][r] + bst[320 + e], 0.f) * bst[352 + e];
    }
    #pragma unroll
    for (int mask = 1; mask <= 8; mask <<= 1) {
        #pragma unroll
        for (int r = 0; r < 4; ++r) yp[r] += __shfl_xor(yp[r], mask);
    }
    if (n == 0) {
        #pragma unroll
        for (int r = 0; r < 4; ++r) ysum[w][g][r] = yp[r];
    }
    __syncthreads();

    if (t < 32) {
        const int mi2 = t >> 4, g2 = (t >> 2) & 3, r2 = t & 3;
        out[sbase + t] = ysum[mi2 * 2][g2][r2] + ysum[mi2 * 2 + 1][g2][r2] + v2_b[0];
    }
}

// -------------------------------------------------- launch
extern "C" void kernel_launch(void* const* d_in, const int* in_sizes, int n_in,
                              void* d_out, int out_size, void* d_ws, size_t ws_size,
                              hipStream_t stream) {
    const float* agent_qs = (const float*)d_in[0];
    const float* states   = (const float*)d_in[1];
    const float* W_heads  = (const float*)d_in[2];
    const float* a_heads  = (const float*)d_in[3];
    const float* W_out    = (const float*)d_in[4];
    const float* a_out    = (const float*)d_in[5];
    const float* hw1_w    = (const float*)d_in[6];
    const float* hw1_b    = (const float*)d_in[7];
    const float* hb1_w    = (const float*)d_in[8];
    const float* hb1_b    = (const float*)d_in[9];
    const float* hwf_w    = (const float*)d_in[10];
    const float* hwf_b    = (const float*)d_in[11];
    const float* v1_w     = (const float*)d_in[12];
    const float* v1_b     = (const float*)d_in[13];
    const float* v2_w     = (const float*)d_in[14];
    const float* v2_b     = (const float*)d_in[15];

    unsigned short* bpack = (unsigned short*)d_ws;         // 360448 B
    float* aux = (float*)((char*)d_ws + AUXOFF);           // +128 B

    pack_b<<<(KSTEPS * NTILE * 64 + 32 + 255) / 256, 256, 0, stream>>>(
        hw1_w, hb1_w, hwf_w, v1_w, W_out, a_out, bpack, aux);
    fused_kernel<<<BT / 32, 256, 0, stream>>>(agent_qs, states,
                                              W_heads, a_heads, W_out, a_out,
                                              bpack, aux,
                                              hw1_b, hb1_b, hwf_b, v1_b, v2_w, v2_b,
                                              (float*)d_out);
}

// Round 13
// 293.231 us; speedup vs baseline: 6.7592x; 1.1484x over previous
//
#include <hip/hip_runtime.h>
#include <hip/hip_bf16.h>
#include <stdint.h>

// QMIX+GAT round 13: GAT layer-2 on MFMA (3x mfma_f32_32x32x16_bf16 per
// sample pair: [hcatA;hcatB]@W_out, then block-diag att@Wh2), c-major
// A-tile with k-permuted B-pack. Head layer + softmax unchanged (R12).
// Ledger: NEVER pass min-waves>=2 in launch_bounds (R4/R7: VGPR 84 + 4.5GB spill).

#define BT       (2048 * 128)
#define ALPHA    0.2f
#define NTILE    22            // 352 / 16
#define KSTEPS   16            // 512 / 32
#define AUXOFF   360448        // byte offset of wa1/wa2 aux table in d_ws

typedef __attribute__((ext_vector_type(8))) short bf16x8;
typedef __attribute__((ext_vector_type(4))) float f32x4;
typedef __attribute__((ext_vector_type(16))) float f32x16;
typedef __attribute__((ext_vector_type(2))) float f32x2;
typedef _Float16 f16x2 __attribute__((ext_vector_type(2)));

__device__ __forceinline__ f32x2 b2(float s) { return (f32x2){s, s}; }
__device__ __forceinline__ f32x2 pkfma(f32x2 a, f32x2 b, f32x2 c) {
    return __builtin_elementwise_fma(a, b, c);
}
__device__ __forceinline__ float elu1(float x) { return x > 0.f ? x : (__expf(x) - 1.f); }

__device__ __forceinline__ unsigned short f32_to_bf16_rne(float x) {
    uint32_t u = __float_as_uint(x);
    u += 0x7fffu + ((u >> 16) & 1u);
    return (unsigned short)(u >> 16);
}

__device__ __forceinline__ float fdot2f(uint32_t a, f16x2 b, float c) {
#if __has_builtin(__builtin_amdgcn_fdot2)
    return __builtin_amdgcn_fdot2(__builtin_bit_cast(f16x2, a), b, c, false);
#else
    const f16x2 av = __builtin_bit_cast(f16x2, a);
    return fmaf((float)av.x, (float)b.x, fmaf((float)av.y, (float)b.y, c));
#endif
}
__device__ __forceinline__ f16x2 pkrtz(float a, float b) {
    return __builtin_bit_cast(f16x2, __builtin_amdgcn_cvt_pkrtz(a, b));
}
__device__ __forceinline__ uint32_t cvtpk_bf16(float lo, float hi) {
    uint32_t r;
    asm("v_cvt_pk_bf16_f32 %0, %1, %2" : "=v"(r) : "v"(lo), "v"(hi));
    return r;
}
__device__ __forceinline__ f32x16 z16() {
    f32x16 r;
    #pragma unroll
    for (int i = 0; i < 16; ++i) r[i] = 0.f;
    return r;
}

// paired softmax over 16 logits e1 + e2[j]; returns {1/sumA, 1/sumB}
__device__ __forceinline__ f32x2 softmax16p(const float* e2A, const float* e2B,
                                            f32x2 e1, f32x2* ee) {
    #pragma unroll
    for (int t4 = 0; t4 < 4; ++t4) {
        const float4 va = *(const float4*)&e2A[t4 * 4];
        const float4 vb = *(const float4*)&e2B[t4 * 4];
        const f32x2 l0 = e1 + (f32x2){va.x, vb.x};
        const f32x2 l1 = e1 + (f32x2){va.y, vb.y};
        const f32x2 l2 = e1 + (f32x2){va.z, vb.z};
        const f32x2 l3 = e1 + (f32x2){va.w, vb.w};
        ee[4*t4+0] = __builtin_elementwise_max(l0, l0 * b2(ALPHA));
        ee[4*t4+1] = __builtin_elementwise_max(l1, l1 * b2(ALPHA));
        ee[4*t4+2] = __builtin_elementwise_max(l2, l2 * b2(ALPHA));
        ee[4*t4+3] = __builtin_elementwise_max(l3, l3 * b2(ALPHA));
    }
    f32x2 m0 = __builtin_elementwise_max(ee[0], ee[1]);
    f32x2 m1 = __builtin_elementwise_max(ee[2], ee[3]);
    f32x2 m2 = __builtin_elementwise_max(ee[4], ee[5]);
    f32x2 m3 = __builtin_elementwise_max(ee[6], ee[7]);
    f32x2 m4 = __builtin_elementwise_max(ee[8], ee[9]);
    f32x2 m5 = __builtin_elementwise_max(ee[10], ee[11]);
    f32x2 m6 = __builtin_elementwise_max(ee[12], ee[13]);
    f32x2 m7 = __builtin_elementwise_max(ee[14], ee[15]);
    m0 = __builtin_elementwise_max(m0, m1); m2 = __builtin_elementwise_max(m2, m3);
    m4 = __builtin_elementwise_max(m4, m5); m6 = __builtin_elementwise_max(m6, m7);
    const f32x2 mx = __builtin_elementwise_max(__builtin_elementwise_max(m0, m2),
                                               __builtin_elementwise_max(m4, m6));
    #pragma unroll
    for (int j = 0; j < 16; ++j) {
        const f32x2 d = ee[j] - mx;
        ee[j] = (f32x2){__expf(d.x), __expf(d.y)};
    }
    f32x2 s0 = ee[0]+ee[1], s1 = ee[2]+ee[3], s2 = ee[4]+ee[5], s3 = ee[6]+ee[7];
    f32x2 s4 = ee[8]+ee[9], s5 = ee[10]+ee[11], s6 = ee[12]+ee[13], s7 = ee[14]+ee[15];
    s0 += s1; s2 += s3; s4 += s5; s6 += s7;
    const f32x2 sum = (s0 + s2) + (s4 + s6);
    return (f32x2){__builtin_amdgcn_rcpf(sum.x), __builtin_amdgcn_rcpf(sum.y)};
}

// -------------------------------------------------- kernel P: pack B + aux
// A-tile k-index is c-major: s'[i] = gat[i&15... n][c=i>>4]; weight row for
// s'[i] is r_old = (i&15)*32 + (i>>4). bpack rows permuted accordingly.
__global__ __launch_bounds__(256) void pack_b(
    const float* __restrict__ hw1_w, const float* __restrict__ hb1_w,
    const float* __restrict__ hwf_w, const float* __restrict__ v1_w,
    const float* __restrict__ W_out, const float* __restrict__ a_out,
    unsigned short* __restrict__ bpack, float* __restrict__ aux)
{
    const int gi = blockIdx.x * 256 + threadIdx.x;
    if (gi < KSTEPS * NTILE * 64) {
        const int l  = gi & 63;
        const int ni = (gi >> 6) % NTILE;
        const int kt = gi / (NTILE * 64);
        const int col = ni * 16 + (l & 15);
        const int k0  = kt * 32 + (l >> 4) * 8;
        const float* src; int stride; int c;
        if (col < 256)      { src = hw1_w; stride = 256; c = col; }
        else if (col < 288) { src = hb1_w; stride = 32;  c = col - 256; }
        else if (col < 320) { src = hwf_w; stride = 32;  c = col - 288; }
        else                { src = v1_w;  stride = 32;  c = col - 320; }
        union { unsigned short u[8]; uint4 v; } pk;
        #pragma unroll
        for (int e = 0; e < 8; ++e) {
            const int i = k0 + e;
            const int r_old = ((i & 15) << 5) + (i >> 4);
            pk.u[e] = f32_to_bf16_rne(src[(long)r_old * stride + c]);
        }
        ((uint4*)bpack)[gi] = pk.v;
    } else if (gi < KSTEPS * NTILE * 64 + 32) {
        const int a = gi - KSTEPS * NTILE * 64;     // 0..31
        const int which = a >> 4, f = a & 15;
        float s = 0.f;
        for (int c = 0; c < 32; ++c) s = fmaf(W_out[f * 32 + c], a_out[which * 32 + c], s);
        aux[a] = s;                                  // wa1[16] | wa2[16]
    }
}

// -------------------------------------------------- kernel F
__global__ __launch_bounds__(256) void fused_kernel(
    const float* __restrict__ agent_qs, const float* __restrict__ states,
    const float* __restrict__ W_heads,  const float* __restrict__ a_heads,
    const float* __restrict__ W_out,    const float* __restrict__ a_out,
    const unsigned short* __restrict__ bpack, const float* __restrict__ aux,
    const float* __restrict__ hw1_b, const float* __restrict__ hb1_b,
    const float* __restrict__ hwf_b, const float* __restrict__ v1_b,
    const float* __restrict__ v2_w,  const float* __restrict__ v2_b,
    float* __restrict__ out)
{
    __shared__ unsigned short A[32][512];  // 32 KB; wave w's rows w*8..+7 serve
                                           // as phase-1 scratch then final gat
    __shared__ float bst[384];
    __shared__ float qs[288];
    __shared__ float ysum[4][4][4];

    const int t    = threadIdx.x;
    const int w    = t >> 6;
    const int lane = t & 63;
    const int g    = lane >> 4;      // sample-in-quad
    const int n    = lane & 15;      // node
    const long sbase = (long)blockIdx.x * 32;

    char* scr = (char*)&A[0][0] + w * 8192;
    // head-phase scratch (dead before layer-2 exchange overwrites regions)
    _Float16* hxA = (_Float16*)(scr + (g * 2)     * 528);
    _Float16* hxB = (_Float16*)(scr + (g * 2 + 1) * 528);
    float*    e2A = (float*)(scr + 4224 + (g * 2)     * 80);
    float*    e2B = (float*)(scr + 4224 + (g * 2 + 1) * 80);

    const int mA = w * 8 + g;
    const int mB = w * 8 + 4 + g;

    // ---------------- phase 1a: GAT heads (unchanged from R12)
    f32x2 xr2[16];
    {
        const float4* xa = (const float4*)(states + (sbase + mA) * 256 + n * 16);
        const float4* xb = (const float4*)(states + (sbase + mB) * 256 + n * 16);
        #pragma unroll
        for (int i = 0; i < 4; ++i) {
            const float4 va = xa[i], vb = xb[i];
            xr2[4*i+0] = (f32x2){va.x, vb.x};
            xr2[4*i+1] = (f32x2){va.y, vb.y};
            xr2[4*i+2] = (f32x2){va.z, vb.z};
            xr2[4*i+3] = (f32x2){va.w, vb.w};
        }
    }

    f32x2 hcat2[16];
    #pragma unroll
    for (int h = 0; h < 4; ++h) {
        f32x2 wh0 = b2(0.f), wh1 = b2(0.f), wh2 = b2(0.f), wh3 = b2(0.f);
        #pragma unroll
        for (int f = 0; f < 16; ++f) {
            const f32x2 xf = xr2[f];
            wh0 = pkfma(xf, b2(W_heads[h*64 + f*4 + 0]), wh0);
            wh1 = pkfma(xf, b2(W_heads[h*64 + f*4 + 1]), wh1);
            wh2 = pkfma(xf, b2(W_heads[h*64 + f*4 + 2]), wh2);
            wh3 = pkfma(xf, b2(W_heads[h*64 + f*4 + 3]), wh3);
        }
        const f32x2 e1 = pkfma(wh0, b2(a_heads[h*8+0]),
                         pkfma(wh1, b2(a_heads[h*8+1]),
                         pkfma(wh2, b2(a_heads[h*8+2]), wh3 * b2(a_heads[h*8+3]))));
        const f32x2 e2 = pkfma(wh0, b2(a_heads[h*8+4]),
                         pkfma(wh1, b2(a_heads[h*8+5]),
                         pkfma(wh2, b2(a_heads[h*8+6]), wh3 * b2(a_heads[h*8+7]))));
        hxA[0*16 + n] = (_Float16)wh0.x;  hxB[0*16 + n] = (_Float16)wh0.y;
        hxA[1*16 + n] = (_Float16)wh1.x;  hxB[1*16 + n] = (_Float16)wh1.y;
        hxA[2*16 + n] = (_Float16)wh2.x;  hxB[2*16 + n] = (_Float16)wh2.y;
        hxA[3*16 + n] = (_Float16)wh3.x;  hxB[3*16 + n] = (_Float16)wh3.y;
        e2A[n] = e2.x;
        e2B[n] = e2.y;

        f32x2 ee[16];
        const f32x2 inv = softmax16p(e2A, e2B, e1, ee);
        f16x2 eA[8], eB[8];
        #pragma unroll
        for (int jp = 0; jp < 8; ++jp) {
            eA[jp] = pkrtz(ee[2*jp].x, ee[2*jp+1].x);
            eB[jp] = pkrtz(ee[2*jp].y, ee[2*jp+1].y);
        }
        #pragma unroll
        for (int k = 0; k < 4; ++k) {
            const uint4 wa0 = *(const uint4*)&hxA[k*16];
            const uint4 wa1 = *(const uint4*)&hxA[k*16 + 8];
            const uint4 wb0 = *(const uint4*)&hxB[k*16];
            const uint4 wb1 = *(const uint4*)&hxB[k*16 + 8];
            float sA = 0.f, sB = 0.f;
            sA = fdot2f(wa0.x, eA[0], sA);  sB = fdot2f(wb0.x, eB[0], sB);
            sA = fdot2f(wa0.y, eA[1], sA);  sB = fdot2f(wb0.y, eB[1], sB);
            sA = fdot2f(wa0.z, eA[2], sA);  sB = fdot2f(wb0.z, eB[2], sB);
            sA = fdot2f(wa0.w, eA[3], sA);  sB = fdot2f(wb0.w, eB[3], sB);
            sA = fdot2f(wa1.x, eA[4], sA);  sB = fdot2f(wb1.x, eB[4], sB);
            sA = fdot2f(wa1.y, eA[5], sA);  sB = fdot2f(wb1.y, eB[5], sB);
            sA = fdot2f(wa1.z, eA[6], sA);  sB = fdot2f(wb1.z, eB[6], sB);
            sA = fdot2f(wa1.w, eA[7], sA);  sB = fdot2f(wb1.w, eB[7], sB);
            hcat2[h*4+k] = (f32x2){elu1(sA * inv.x), elu1(sB * inv.y)};
        }
    }

    // ---------------- phase 1b: layer-2 softmax (e-folds via aux)
    f32x2 e1o = b2(0.f), e2o = b2(0.f);
    #pragma unroll
    for (int f = 0; f < 16; ++f) {
        e1o = pkfma(hcat2[f], b2(aux[f]), e1o);
        e2o = pkfma(hcat2[f], b2(aux[16 + f]), e2o);
    }
    e2A[n] = e2o.x;
    e2B[n] = e2o.y;
    f32x2 ee[16];
    const f32x2 invo = softmax16p(e2A, e2B, e1o, ee);
    #pragma unroll
    for (int j = 0; j < 16; ++j) ee[j] *= invo;      // fold 1/sum into att

    // ---------------- phase 1c: exchange hcat (row g) and att (row 4+g) as bf16
    {
        uint32_t hA[8], hB[8], aAv[8], aBv[8];
        #pragma unroll
        for (int p2 = 0; p2 < 8; ++p2) {
            hA[p2]  = cvtpk_bf16(hcat2[2*p2].x, hcat2[2*p2+1].x);
            hB[p2]  = cvtpk_bf16(hcat2[2*p2].y, hcat2[2*p2+1].y);
            aAv[p2] = cvtpk_bf16(ee[2*p2].x, ee[2*p2+1].x);
            aBv[p2] = cvtpk_bf16(ee[2*p2].y, ee[2*p2+1].y);
        }
        char* hb = scr + g * 1024;          // hcatA[16][32B] | hcatB
        char* ab = scr + (4 + g) * 1024;    // attA | attB
        uint4 v;
        v.x=hA[0]; v.y=hA[1]; v.z=hA[2]; v.w=hA[3];  *(uint4*)(hb + n*32)       = v;
        v.x=hA[4]; v.y=hA[5]; v.z=hA[6]; v.w=hA[7];  *(uint4*)(hb + n*32 + 16)  = v;
        v.x=hB[0]; v.y=hB[1]; v.z=hB[2]; v.w=hB[3];  *(uint4*)(hb + 512 + n*32) = v;
        v.x=hB[4]; v.y=hB[5]; v.z=hB[6]; v.w=hB[7];  *(uint4*)(hb + 512 + n*32 + 16) = v;
        v.x=aAv[0];v.y=aAv[1];v.z=aAv[2];v.w=aAv[3]; *(uint4*)(ab + n*32)       = v;
        v.x=aAv[4];v.y=aAv[5];v.z=aAv[6];v.w=aAv[7]; *(uint4*)(ab + n*32 + 16)  = v;
        v.x=aBv[0];v.y=aBv[1];v.z=aBv[2];v.w=aBv[3]; *(uint4*)(ab + 512 + n*32) = v;
        v.x=aBv[4];v.y=aBv[5];v.z=aBv[6];v.w=aBv[7]; *(uint4*)(ab + 512 + n*32 + 16) = v;
    }

    // ---------------- phase 1d: 3 MFMAs per pair, looped over the 4 pairs
    const int row  = lane & 31;
    const int half = lane >> 5;
    bf16x8 wf;                      // W_out B-frag: B[k=half*8+e][col=row]
    {
        union { uint32_t d[4]; bf16x8 v; } u;
        #pragma unroll
        for (int e = 0; e < 4; ++e)
            u.d[e] = cvtpk_bf16(W_out[(half*8 + 2*e)*32 + row],
                                W_out[(half*8 + 2*e + 1)*32 + row]);
        wf = u.v;
    }

    #pragma unroll 1
    for (int gg = 0; gg < 4; ++gg) {
        const char* hb = scr + gg * 1024;
        const char* ab = scr + (4 + gg) * 1024;
        // step1: D1 = [hcatA; hcatB] @ W_out  (rows 0-15 Wh2A, 16-31 Wh2B)
        uint4 af1u = *(const uint4*)(hb + (row & 15) * 32 + (row >> 4) * 512 + half * 16);
        bf16x8 af1; memcpy(&af1, &af1u, 16);
        f32x16 D1 = __builtin_amdgcn_mfma_f32_32x32x16_bf16(af1, wf, z16(), 0, 0, 0);

        // D1 -> B-frags for step2 (lane<->lane+32 via shfl_xor 32)
        const uint32_t d0 = cvtpk_bf16(D1[0], D1[1]),   d1 = cvtpk_bf16(D1[2], D1[3]);
        const uint32_t d2 = cvtpk_bf16(D1[4], D1[5]),   d3 = cvtpk_bf16(D1[6], D1[7]);
        const uint32_t f0 = cvtpk_bf16(D1[8], D1[9]),   f1 = cvtpk_bf16(D1[10], D1[11]);
        const uint32_t f2 = cvtpk_bf16(D1[12], D1[13]), f3 = cvtpk_bf16(D1[14], D1[15]);
        const uint32_t x0 = (uint32_t)__shfl_xor((int)d0, 32);
        const uint32_t x1 = (uint32_t)__shfl_xor((int)d1, 32);
        const uint32_t x2 = (uint32_t)__shfl_xor((int)d2, 32);
        const uint32_t x3 = (uint32_t)__shfl_xor((int)d3, 32);
        const uint32_t y0 = (uint32_t)__shfl_xor((int)f0, 32);
        const uint32_t y1 = (uint32_t)__shfl_xor((int)f1, 32);
        const uint32_t y2 = (uint32_t)__shfl_xor((int)f2, 32);
        const uint32_t y3 = (uint32_t)__shfl_xor((int)f3, 32);
        union { uint32_t d[4]; bf16x8 v; } b1u, b2u;
        if (half == 0) {
            b1u.d[0]=d0; b1u.d[1]=d1; b1u.d[2]=x0; b1u.d[3]=x1;
            b2u.d[0]=f0; b2u.d[1]=f1; b2u.d[2]=y0; b2u.d[3]=y1;
        } else {
            b1u.d[0]=x2; b1u.d[1]=x3; b1u.d[2]=d2; b1u.d[3]=d3;
            b2u.d[0]=y2; b2u.d[1]=y3; b2u.d[2]=f2; b2u.d[3]=f3;
        }

        // step2 A-frags: [attA; 0] and [0; attB]
        uint4 aau = {0,0,0,0}, abu = {0,0,0,0};
        if (row < 16) aau = *(const uint4*)(ab + row * 32 + half * 16);
        else          abu = *(const uint4*)(ab + 512 + (row - 16) * 32 + half * 16);
        bf16x8 aaf, abf; memcpy(&aaf, &aau, 16); memcpy(&abf, &abu, 16);
        f32x16 D2 = __builtin_amdgcn_mfma_f32_32x32x16_bf16(aaf, b1u.v, z16(), 0, 0, 0);
        D2 = __builtin_amdgcn_mfma_f32_32x32x16_bf16(abf, b2u.v, D2, 0, 0, 0);

        // epilogue: elu, pack, store c-major with rotation map
        const int c = row;
        const int mAg = w * 8 + gg, mBg = w * 8 + 4 + gg;
        const uint32_t pA0 = cvtpk_bf16(elu1(D2[0]),  elu1(D2[1]));
        const uint32_t pA1 = cvtpk_bf16(elu1(D2[2]),  elu1(D2[3]));
        const uint32_t pA2 = cvtpk_bf16(elu1(D2[4]),  elu1(D2[5]));
        const uint32_t pA3 = cvtpk_bf16(elu1(D2[6]),  elu1(D2[7]));
        const uint32_t pB0 = cvtpk_bf16(elu1(D2[8]),  elu1(D2[9]));
        const uint32_t pB1 = cvtpk_bf16(elu1(D2[10]), elu1(D2[11]));
        const uint32_t pB2 = cvtpk_bf16(elu1(D2[12]), elu1(D2[13]));
        const uint32_t pB3 = cvtpk_bf16(elu1(D2[14]), elu1(D2[15]));
        const int u0 = 2 * c, u1 = 2 * c + 1;
        const int pa0 = (((u0 & 3) << 4) + (u0 >> 2) + mAg) & 63;
        const int pa1 = (((u1 & 3) << 4) + (u1 >> 2) + mAg) & 63;
        const int pb0 = (((u0 & 3) << 4) + (u0 >> 2) + mBg) & 63;
        const int pb1 = (((u1 & 3) << 4) + (u1 >> 2) + mBg) & 63;
        uint2 wv;
        wv.x = pA0; wv.y = pA1;
        *(uint2*)((char*)&A[0][0] + mAg * 1024 + pa0 * 16 + half * 8) = wv;
        wv.x = pA2; wv.y = pA3;
        *(uint2*)((char*)&A[0][0] + mAg * 1024 + pa1 * 16 + half * 8) = wv;
        wv.x = pB0; wv.y = pB1;
        *(uint2*)((char*)&A[0][0] + mBg * 1024 + pb0 * 16 + half * 8) = wv;
        wv.x = pB2; wv.y = pB3;
        *(uint2*)((char*)&A[0][0] + mBg * 1024 + pb1 * 16 + half * 8) = wv;
    }

    __syncthreads();   // all A rows final

    // ---- stage phase-3 tables into registers (loads overlap MFMA loop)
    const float bv0 = hw1_b[t];
    float bv1 = 0.f;
    if (t < 32)       bv1 = hb1_b[t];
    else if (t < 64)  bv1 = hwf_b[t - 32];
    else if (t < 96)  bv1 = v1_b[t - 64];
    else if (t < 128) bv1 = v2_w[t - 96];
    const float qv = agent_qs[sbase * 8 + t];

    // ---------------- phase 2: MFMA GEMM, parity-split n-tiles (validated)
    const int mi  = w >> 1;
    const int pr  = w & 1;
    const int arow = mi * 16 + n;

    f32x4 acc[11];
    #pragma unroll
    for (int j = 0; j < 11; ++j) acc[j] = (f32x4){0.f, 0.f, 0.f, 0.f};

    const uint4* Bb = (const uint4*)bpack + lane;
    for (int kt = 0; kt < KSTEPS; ++kt) {
        const int chunk = (g * 16 + kt + arow) & 63;
        bf16x8 af = *(const bf16x8*)((const char*)&A[0][0] + arow * 1024 + chunk * 16);
        const uint4* bp = Bb + (kt * NTILE + pr) * 64;
        #pragma unroll
        for (int j = 0; j < 11; ++j) {
            uint4 bw = bp[(2 * j) * 64];
            bf16x8 bf;
            memcpy(&bf, &bw, 16);
            acc[j] = __builtin_amdgcn_mfma_f32_16x16x32_bf16(af, bf, acc[j], 0, 0, 0);
        }
    }

    // ---- write staged phase-3 tables
    bst[t] = bv0;
    if (t < 128) bst[256 + t] = bv1;
    qs[(t >> 3) * 9 + (t & 7)] = qv;
    __syncthreads();

    // ---------------- phase 3: epilogue from accumulators (validated)
    const int e = pr * 16 + n;
    float yp[4];
    #pragma unroll
    for (int r = 0; r < 4; ++r) {
        const int ms = mi * 16 + g * 4 + r;
        float hs = acc[8][r] + bst[256 + e];
        #pragma unroll
        for (int a = 0; a < 8; ++a)
            hs = fmaf(qs[ms * 9 + a], fabsf(acc[a][r] + bst[a * 32 + e]), hs);
        const float hid = elu1(hs);
        yp[r] = hid * fabsf(acc[9][r] + bst[288 + e])
              + fmaxf(acc[10][r] + bst[320 + e], 0.f) * bst[352 + e];
    }
    #pragma unroll
    for (int mask = 1; mask <= 8; mask <<= 1) {
        #pragma unroll
        for (int r = 0; r < 4; ++r) yp[r] += __shfl_xor(yp[r], mask);
    }
    if (n == 0) {
        #pragma unroll
        for (int r = 0; r < 4; ++r) ysum[w][g][r] = yp[r];
    }
    __syncthreads();

    if (t < 32) {
        const int mi2 = t >> 4, g2 = (t >> 2) & 3, r2 = t & 3;
        out[sbase + t] = ysum[mi2 * 2][g2][r2] + ysum[mi2 * 2 + 1][g2][r2] + v2_b[0];
    }
}

// -------------------------------------------------- launch
extern "C" void kernel_launch(void* const* d_in, const int* in_sizes, int n_in,
                              void* d_out, int out_size, void* d_ws, size_t ws_size,
                              hipStream_t stream) {
    const float* agent_qs = (const float*)d_in[0];
    const float* states   = (const float*)d_in[1];
    const float* W_heads  = (const float*)d_in[2];
    const float* a_heads  = (const float*)d_in[3];
    const float* W_out    = (const float*)d_in[4];
    const float* a_out    = (const float*)d_in[5];
    const float* hw1_w    = (const float*)d_in[6];
    const float* hw1_b    = (const float*)d_in[7];
    const float* hb1_w    = (const float*)d_in[8];
    const float* hb1_b    = (const float*)d_in[9];
    const float* hwf_w    = (const float*)d_in[10];
    const float* hwf_b    = (const float*)d_in[11];
    const float* v1_w     = (const float*)d_in[12];
    const float* v1_b     = (const float*)d_in[13];
    const float* v2_w     = (const float*)d_in[14];
    const float* v2_b     = (const float*)d_in[15];

    unsigned short* bpack = (unsigned short*)d_ws;         // 360448 B
    float* aux = (float*)((char*)d_ws + AUXOFF);           // +128 B

    pack_b<<<(KSTEPS * NTILE * 64 + 32 + 255) / 256, 256, 0, stream>>>(
        hw1_w, hb1_w, hwf_w, v1_w, W_out, a_out, bpack, aux);
    fused_kernel<<<BT / 32, 256, 0, stream>>>(agent_qs, states,
                                              W_heads, a_heads, W_out, a_out,
                                              bpack, aux,
                                              hw1_b, hb1_b, hwf_b, v1_b, v2_w, v2_b,
                                              (float*)d_out);
}